// Round 14
// baseline (212.542 us; speedup 1.0000x reference)
//
#include <hip/hip_runtime.h>
#include <hip/hip_bf16.h>
#include <stdint.h>

typedef __attribute__((ext_vector_type(8))) short bf16x8;
typedef __attribute__((ext_vector_type(4))) float f32x4;

__device__ __forceinline__ float blo(unsigned u){ union{float f;unsigned x;}v; v.x = u<<16; return v.f; }
__device__ __forceinline__ float bhi(unsigned u){ union{float f;unsigned x;}v; v.x = u & 0xFFFF0000u; return v.f; }
__device__ __forceinline__ unsigned short f2bf(float f){
  union{float f;unsigned x;}v; v.f=f; unsigned x=v.x;
  return (unsigned short)((x + 0x7fffu + ((x>>16)&1u)) >> 16);
}
__device__ __forceinline__ unsigned cvtpk(float lo, float hi){
  unsigned r;
  asm("v_cvt_pk_bf16_f32 %0, %1, %2" : "=v"(r) : "v"(lo), "v"(hi));
  return r;
}

// ---------------- ROI max-pool + token build + wT pack ----------------
// pooled: [n][c][l] (natural c*49+l K-order); tok: [n][l][c]
__global__ __launch_bounds__(256) void pool_pack_kernel(
    const float* __restrict__ rois,
    const float* __restrict__ fm0, const float* __restrict__ fm1,
    const float* __restrict__ fm2, const float* __restrict__ fm3,
    float* __restrict__ pooled, unsigned short* __restrict__ tok,
    const float* __restrict__ wreg, const float* __restrict__ wcls, float* __restrict__ wT)
{
  int bx = blockIdx.x;
  int tid = threadIdx.x;
  if (bx >= 896){
    int c = bx - 896;   // 0..104
    if (c < 84){
      for (int k = tid; k < 2048; k += 256) wT[(size_t)c*2048 + k] = wreg[(size_t)k*84 + c];
    } else {
      int cc = c - 84;
      for (int k = tid; k < 2048; k += 256) wT[(size_t)c*2048 + k] = wcls[(size_t)k*21 + cc];
    }
    return;
  }
  int n = bx / 7;            // roi
  int ph = bx - n*7;         // 0..6
  int c = tid;               // channel
  const float* r = rois + n*4;
  int b = n >> 6;
  float rx1=r[0], ry1=r[1], rx2=r[2], ry2=r[3];
  float size = sqrtf((rx2-rx1)*(ry2-ry1));
  int lvl = (int)(3.0f + logf(size/224.0f));
  if (lvl < 0) lvl = 0; if (lvl > 3) lvl = 3;
  const float strides_[4] = {4.f,8.f,16.f,32.f};
  const int hw_[4] = {160,80,40,20};
  float s = strides_[lvl]; int Hl = hw_[lvl];
  int x1 = (int)(rx1/s), y1 = (int)(ry1/s), x2 = (int)(rx2/s), y2 = (int)(ry2/s);
  #pragma unroll
  for (int it=0; it<7; ++it){
    bool need = (y2-y1+1) < 7;
    if (need){ y1 = (y1-1 > 0) ? y1-1 : 0; y2 = (y2+1 < Hl-1) ? y2+1 : Hl-1; }
  }
  #pragma unroll
  for (int it=0; it<7; ++it){
    bool need = (x2-x1+1) < 7;
    if (need){ x1 = (x1-1 > 0) ? x1-1 : 0; x2 = (x2+1 < Hl-1) ? x2+1 : Hl-1; }
  }
  int rh = y2-y1+1, rw = x2-x1+1;
  int kh = (rh+6)/7, sh = rh/7, kw = (rw+6)/7, sw2 = rw/7;
  const float* fm = (lvl==0)?fm0:(lvl==1)?fm1:(lvl==2)?fm2:fm3;
  const float* fp = fm + ((size_t)(b*256 + c))*(size_t)(Hl*Hl);
  int r0 = y1 + ph*sh;
  for (int pw=0; pw<7; ++pw){
    int c0 = x1 + pw*sw2;
    float m = -3.4e38f;
    for (int i=0;i<kh;++i){
      const float* rp = fp + (size_t)(r0+i)*Hl + c0;
      for (int j=0;j<kw;++j) m = fmaxf(m, rp[j]);
    }
    int l = ph*7+pw;
    pooled[((size_t)n*256 + c)*49 + l] = m;
    tok[((size_t)n*49 + l)*256 + c] = f2bf(m);
  }
}

// ---------------- bf16 MFMA GEMM + natural-k weight-conversion tail ----------------
// Pages: P[pr][2048 shorts], pr = (k>>5)*32 + bn; within-page idx = kr*64 + ((bcg*8)^((kr>>3)<<4)) + j
// == byte-identical to the swizzled LDS image -> GEMM staging = 1 contiguous uint4/thread.
// Conversion tail (natural k, both sides streaming): one WAVE per page row; lane L writes
// uint4 slots L, L+64, L+128, L+192 (1 KB contiguous/store). Slot s content: kr=s>>3,
// bcg=(s&7)^((kr>>3)<<1); algebra: kr*64 + ((bcg*8)^((kr>>3)<<4)) == s*8. Reads: 8 lanes
// cover one w1 row's 256 B slice (natural row order, no gather).
// BSRC 0: B f32 staged via float4+cvt (macro-128). BSRC 1: B = bf16 pages.
// XCDR: kc-slab co-residency remap (halves FETCH via L2 dedup of the 2x bm duplication).
// EPI 0: out = val + bias. EPI 1: O-proj x[n][c*49+l] = val + bias + pooled[n][c][l].
// EPI 2: plain-store split-K partial.
template<int EPI, int BSRC, bool XCDR>
__global__ __launch_bounds__(256) void gemm_kernel(
    const unsigned short* __restrict__ A,
    const float* __restrict__ B0, const float* __restrict__ B1, const float* __restrict__ B2,
    const unsigned short* __restrict__ Bpre,
    const float* __restrict__ bias0, const float* __restrict__ bias1, const float* __restrict__ bias2,
    unsigned short* __restrict__ o0, unsigned short* __restrict__ o1, unsigned short* __restrict__ o2,
    float* __restrict__ outf, const float* __restrict__ pooled,
    int M, int Nper, int K, int nM, int nN, int kChunk,
    int nGemm, const float* __restrict__ convW, unsigned short* __restrict__ convP)
{
  int tid = threadIdx.x;
  if ((int)blockIdx.x >= nGemm){
    // ---- conversion tail: wave-per-page-row, natural k, contiguous both sides ----
    int cb = blockIdx.x - nGemm;
    int wv = tid >> 6, lane = tid & 63;
    int krBase = lane >> 3;         // 0..7
    int bcgS = lane & 7;
    #pragma unroll
    for (int pass = 0; pass < 4; ++pass){
      int pr = cb*16 + pass*4 + wv;           // page row index
      int k32 = pr >> 5, bn = pr & 31;
      uint4 vout0, vout1, vout2, vout3;
      #pragma unroll
      for (int q = 0; q < 4; ++q){
        int kr = krBase + (q<<3);
        int bcg = bcgS ^ ((kr>>3)<<1);
        const float* srow = convW + (size_t)(k32*32 + kr)*2048 + bn*64;   // natural row
        float4 a = *(const float4*)(srow + bcg*8);
        float4 b = *(const float4*)(srow + bcg*8 + 4);
        uint4 w;
        w.x = cvtpk(a.x,a.y); w.y = cvtpk(a.z,a.w);
        w.z = cvtpk(b.x,b.y); w.w = cvtpk(b.z,b.w);
        if (q==0) vout0 = w; else if (q==1) vout1 = w; else if (q==2) vout2 = w; else vout3 = w;
      }
      uint4* dst = (uint4*)(convP + (size_t)pr*2048);
      dst[lane      ] = vout0;
      dst[lane +  64] = vout1;
      dst[lane + 128] = vout2;
      dst[lane + 192] = vout3;
    }
    return;
  }

  __shared__ __align__(16) unsigned short Bs[2][2048];
  int bid = blockIdx.x;
  if constexpr (XCDR){
    int pe = gridDim.x >> 3;
    bid = (bid & 7)*pe + (bid >> 3);
  }
  int per = nM*nN;
  int kc  = bid / per;
  int rem = bid - kc*per;
  int bm = rem % nM, bn = rem / nM;
  int m0 = bm*64, n0 = bn*64;
  int mat = n0 / Nper;
  int col0 = n0 - mat*Nper;
  const float* Bp    = (mat==0)?B0:(mat==1)?B1:B2;
  const float* biasp = (mat==0)?bias0:(mat==1)?bias1:bias2;
  unsigned short* outp = (mat==0)?o0:(mat==1)?o1:o2;
  int k0 = kc*kChunk;
  int nMacro = kChunk >> 7;
  int lane = tid & 63, wave = tid >> 6;
  int wm = wave & 1, wn = wave >> 1;
  int g = lane >> 4, c = lane & 15;

  f32x4 acc[2][2];
  #pragma unroll
  for (int i=0;i<2;++i)
    #pragma unroll
    for (int j=0;j<2;++j){ acc[i][j][0]=0.f; acc[i][j][1]=0.f; acc[i][j][2]=0.f; acc[i][j][3]=0.f; }

  int brow = tid >> 3, bcg = tid & 7;
  int bw_idx = brow*64 + ((bcg*8) ^ ((brow>>3)<<4));
  const float* Bbase = Bp + (size_t)brow*Nper + col0 + bcg*8;
  const unsigned short* Pbase = Bpre + (size_t)bn*2048 + tid*8;
  int rb0 = g*512 + (((wn*2  )^g)*16 + c);
  int rb1 = g*512 + (((wn*2+1)^g)*16 + c);
  const unsigned short* Ap0 = A + (size_t)(m0 + wm*32 +      c)*K + g*8;
  const unsigned short* Ap1 = A + (size_t)(m0 + wm*32 + 16 + c)*K + g*8;

  auto writeBf32 = [&](int buf, const float4& bx, const float4& by){
    uint4 w;
    w.x = cvtpk(bx.x,bx.y); w.y = cvtpk(bx.z,bx.w);
    w.z = cvtpk(by.x,by.y); w.w = cvtpk(by.z,by.w);
    *(uint4*)&Bs[buf][bw_idx] = w;
  };
  auto writeBpre = [&](int buf, const uint4& v){
    *(uint4*)&Bs[buf][tid*8] = v;
  };
  auto readFrags = [&](int buf, bf16x8& r0, bf16x8& r1){
    union { unsigned short s[8]; bf16x8 v; } u0, u1;
    const unsigned short* bsp = &Bs[buf][0];
    #pragma unroll
    for (int j=0;j<8;++j){ u0.s[j] = bsp[rb0 + j*64]; u1.s[j] = bsp[rb1 + j*64]; }
    r0 = u0.v; r1 = u1.v;
  };
  auto mfma4 = [&](const bf16x8& f0, const bf16x8& f1, const bf16x8& q0, const bf16x8& q1){
    acc[0][0] = __builtin_amdgcn_mfma_f32_16x16x32_bf16(f0,q0,acc[0][0],0,0,0);
    acc[0][1] = __builtin_amdgcn_mfma_f32_16x16x32_bf16(f0,q1,acc[0][1],0,0,0);
    acc[1][0] = __builtin_amdgcn_mfma_f32_16x16x32_bf16(f1,q0,acc[1][0],0,0,0);
    acc[1][1] = __builtin_amdgcn_mfma_f32_16x16x32_bf16(f1,q1,acc[1][1],0,0,0);
  };

  for (int mi = 0; mi < nMacro; ++mi){
    int kk = k0 + (mi << 7);
    uint4 a0x = *(const uint4*)(Ap0+kk),    a0y = *(const uint4*)(Ap1+kk);
    uint4 a1x = *(const uint4*)(Ap0+kk+32), a1y = *(const uint4*)(Ap1+kk+32);
    uint4 a2x = *(const uint4*)(Ap0+kk+64), a2y = *(const uint4*)(Ap1+kk+64);
    uint4 a3x = *(const uint4*)(Ap0+kk+96), a3y = *(const uint4*)(Ap1+kk+96);

    float4 b0a,b0b,b1a,b1b,b2a,b2b,b3a,b3b;
    uint4 v0,v1,v2,v3;
    if constexpr (BSRC==0){
      const float* p0 = Bbase + (size_t)kk*Nper;
      const float* p1 = p0 + (size_t)32*Nper;
      const float* p2 = p0 + (size_t)64*Nper;
      const float* p3 = p0 + (size_t)96*Nper;
      b0a = *(const float4*)p0; b0b = *(const float4*)(p0+4);
      b1a = *(const float4*)p1; b1b = *(const float4*)(p1+4);
      b2a = *(const float4*)p2; b2b = *(const float4*)(p2+4);
      b3a = *(const float4*)p3; b3b = *(const float4*)(p3+4);
    } else {
      const unsigned short* q = Pbase + (size_t)(kk>>5)*65536;   // ((k>>5)*32+bn)*2048
      v0 = *(const uint4*)q;
      v1 = *(const uint4*)(q + 65536);
      v2 = *(const uint4*)(q + 131072);
      v3 = *(const uint4*)(q + 196608);
    }

    if constexpr (BSRC==0) writeBf32(0,b0a,b0b); else writeBpre(0,v0);
    __syncthreads();

    bf16x8 q0,q1;
    readFrags(0,q0,q1);
    if constexpr (BSRC==0) writeBf32(1,b1a,b1b); else writeBpre(1,v1);
    mfma4(*(const bf16x8*)&a0x, *(const bf16x8*)&a0y, q0,q1);
    __syncthreads();

    readFrags(1,q0,q1);
    if constexpr (BSRC==0) writeBf32(0,b2a,b2b); else writeBpre(0,v2);
    mfma4(*(const bf16x8*)&a1x, *(const bf16x8*)&a1y, q0,q1);
    __syncthreads();

    readFrags(0,q0,q1);
    if constexpr (BSRC==0) writeBf32(1,b3a,b3b); else writeBpre(1,v3);
    mfma4(*(const bf16x8*)&a2x, *(const bf16x8*)&a2y, q0,q1);
    __syncthreads();

    readFrags(1,q0,q1);
    mfma4(*(const bf16x8*)&a3x, *(const bf16x8*)&a3y, q0,q1);
  }

  int rq = g << 2, cl = c;
  #pragma unroll
  for (int mr=0;mr<2;++mr){
    #pragma unroll
    for (int nc=0;nc<2;++nc){
      int rowb = m0 + wm*32 + mr*16 + rq;
      int colM = col0 + wn*32 + nc*16 + cl;
      #pragma unroll
      for (int r2=0;r2<4;++r2){
        float v = acc[mr][nc][r2];
        int rr = rowb + r2;
        if constexpr (EPI==0){
          v += biasp[colM];
          outp[(size_t)rr*Nper + colM] = f2bf(v);
        } else if constexpr (EPI==1){
          v += biasp[colM];
          int nn = rr/49, l = rr - nn*49;
          v += pooled[((size_t)nn*256 + colM)*49 + l];
          outp[(size_t)nn*12544 + colM*49 + l] = f2bf(v);
        } else {
          outf[(size_t)kc*M*Nper + (size_t)rr*Nper + colM] = v;
        }
      }
    }
  }
}

// ---------------- split-K reduce kernels ----------------
__global__ __launch_bounds__(256) void reduce1_kernel(
    const float* __restrict__ part, const float* __restrict__ b1,
    unsigned short* __restrict__ h1, int nPart)
{
  int i = blockIdx.x*256 + threadIdx.x;      // float4 index, 65536 total
  float4 s = ((const float4*)part)[i];
  for (int kc = 1; kc < nPart; ++kc){
    float4 p = ((const float4*)part)[(size_t)kc*65536 + i];
    s.x += p.x; s.y += p.y; s.z += p.z; s.w += p.w;
  }
  float4 bb = *(const float4*)(b1 + ((i<<2) & 2047));
  s.x = fmaxf(s.x+bb.x,0.f); s.y = fmaxf(s.y+bb.y,0.f);
  s.z = fmaxf(s.z+bb.z,0.f); s.w = fmaxf(s.w+bb.w,0.f);
  uint2 w;
  w.x = cvtpk(s.x, s.y); w.y = cvtpk(s.z, s.w);
  *(uint2*)&h1[(size_t)i<<2] = w;
}

__global__ __launch_bounds__(256) void reduce2_kernel(
    const float* __restrict__ part, float* __restrict__ h2f, int nPart)
{
  int i = blockIdx.x*256 + threadIdx.x;
  float4 s = ((const float4*)part)[i];
  for (int kc = 1; kc < nPart; ++kc){
    float4 p = ((const float4*)part)[(size_t)kc*65536 + i];
    s.x += p.x; s.y += p.y; s.z += p.z; s.w += p.w;
  }
  ((float4*)h2f)[i] = s;
}

// ---------------- per-ROI attention: 2 blocks/roi, padded K/V rows ----------------
__global__ __launch_bounds__(256) void attn_kernel(
    const unsigned short* __restrict__ Q, const unsigned short* __restrict__ Km,
    const unsigned short* __restrict__ V, unsigned short* __restrict__ ctx)
{
  int n = blockIdx.x, half = blockIdx.y, tid = threadIdx.x;
  int r0 = half*25, rcnt = half ? 24 : 25;
  __shared__ __align__(16) unsigned short qs[25*256];
  __shared__ __align__(16) unsigned short ks[49*260];
  __shared__ float S[25*49];
  const uint4* qg = (const uint4*)(Q + ((size_t)n*49 + r0)*256);
  for (int i = tid; i < rcnt*32; i += 256) ((uint4*)qs)[i] = qg[i];
  const uint2* kg = (const uint2*)(Km + (size_t)n*49*256);
  for (int i = tid; i < 49*64; i += 256){
    int j = i >> 6, s = i & 63;
    *(uint2*)(ks + j*260 + s*4) = kg[i];
  }
  __syncthreads();
  for (int p = tid; p < rcnt*49; p += 256){
    int i = p/49, j = p - i*49;
    const uint2* qr = (const uint2*)(qs + i*256);
    const uint2* kr = (const uint2*)(ks + j*260);
    float sum = 0.f;
    #pragma unroll 8
    for (int c4 = 0; c4 < 64; ++c4){
      uint2 qv = qr[c4], kv = kr[c4];
      sum += blo(qv.x)*blo(kv.x) + bhi(qv.x)*bhi(kv.x);
      sum += blo(qv.y)*blo(kv.y) + bhi(qv.y)*bhi(kv.y);
    }
    S[p] = sum * (1.0f/16.0f);
  }
  __syncthreads();
  const uint2* vg = (const uint2*)(V + (size_t)n*49*256);
  for (int i = tid; i < 49*64; i += 256){
    int j = i >> 6, s = i & 63;
    *(uint2*)(ks + j*260 + s*4) = vg[i];
  }
  if (tid < rcnt){
    float* row = S + tid*49;
    float mx = row[0];
    for (int j=1;j<49;++j) mx = fmaxf(mx,row[j]);
    float sm = 0.f;
    for (int j=0;j<49;++j){ float e = expf(row[j]-mx); row[j]=e; sm+=e; }
    float inv = 1.0f/sm;
    for (int j=0;j<49;++j) row[j] *= inv;
  }
  __syncthreads();
  for (int idx = tid; idx < rcnt*64; idx += 256){
    int i = idx >> 6, cp4 = idx & 63;
    const float* att = S + i*49;
    float s0=0.f, s1=0.f, s2=0.f, s3=0.f;
    #pragma unroll 7
    for (int j=0;j<49;++j){
      uint2 v = *(const uint2*)(ks + j*260 + cp4*4);
      float a = att[j];
      s0 += a*blo(v.x); s1 += a*bhi(v.x);
      s2 += a*blo(v.y); s3 += a*bhi(v.y);
    }
    uint2 outw;
    outw.x = (unsigned)f2bf(s0) | ((unsigned)f2bf(s1) << 16);
    outw.y = (unsigned)f2bf(s2) | ((unsigned)f2bf(s3) << 16);
    *(uint2*)&ctx[((size_t)n*49 + r0 + i)*256 + cp4*4] = outw;
  }
}

// ---------------- heads: fused bias+relu on h2f ----------------
__global__ __launch_bounds__(256) void heads_dot(
    const float* __restrict__ h2f, const float* __restrict__ b2,
    const float* __restrict__ wT,
    const float* __restrict__ breg, const float* __restrict__ bcls,
    float* __restrict__ out, float* __restrict__ logits)
{
  int gw = (blockIdx.x*256 + threadIdx.x) >> 6;
  int lane = threadIdx.x & 63;
  int m = gw / 105, c = gw - m*105;
  const float4* hp = (const float4*)(h2f + (size_t)m*2048);
  const float4* bp = (const float4*)b2;
  const float4* wp = (const float4*)(wT + (size_t)c*2048);
  float sum = 0.f;
  #pragma unroll
  for (int i=0;i<8;++i){
    float4 a = hp[i*64 + lane];
    float4 bb = bp[i*64 + lane];
    float4 w = wp[i*64 + lane];
    sum += fmaxf(a.x+bb.x,0.f)*w.x + fmaxf(a.y+bb.y,0.f)*w.y
         + fmaxf(a.z+bb.z,0.f)*w.z + fmaxf(a.w+bb.w,0.f)*w.w;
  }
  #pragma unroll
  for (int off=32; off; off>>=1) sum += __shfl_down(sum, off, 64);
  if (lane == 0){
    if (c < 84) out[(size_t)m*84 + c] = sum + breg[c];
    else        logits[(size_t)m*21 + (c-84)] = sum + bcls[c-84];
  }
}

__global__ __launch_bounds__(128) void cls_softmax(
    const float* __restrict__ logits, float* __restrict__ out)
{
  int m = threadIdx.x;
  const float* lg = logits + (size_t)m*21;
  float mx = lg[0];
  #pragma unroll
  for (int j=1;j<21;++j) mx = fmaxf(mx, lg[j]);
  float sm = 0.f;
  float e[21];
  #pragma unroll
  for (int j=0;j<21;++j){ e[j] = expf(lg[j]-mx); sm += e[j]; }
  float inv = 1.0f/sm;
  #pragma unroll
  for (int j=0;j<21;++j) out[10752 + (size_t)m*21 + j] = e[j]*inv;
}

extern "C" void kernel_launch(void* const* d_in, const int* in_sizes, int n_in,
                              void* d_out, int out_size, void* d_ws, size_t ws_size,
                              hipStream_t stream)
{
  (void)in_sizes; (void)n_in; (void)out_size; (void)ws_size;
  const float* rois = (const float*)d_in[0];
  const float* fm0  = (const float*)d_in[1];
  const float* fm1  = (const float*)d_in[2];
  const float* fm2  = (const float*)d_in[3];
  const float* fm3  = (const float*)d_in[4];
  const float* wq   = (const float*)d_in[5];
  const float* bq   = (const float*)d_in[6];
  const float* wk   = (const float*)d_in[7];
  const float* bk   = (const float*)d_in[8];
  const float* wv   = (const float*)d_in[9];
  const float* bv   = (const float*)d_in[10];
  const float* wo   = (const float*)d_in[11];
  const float* bo   = (const float*)d_in[12];
  const float* w1   = (const float*)d_in[13];
  const float* b1   = (const float*)d_in[14];
  const float* w2   = (const float*)d_in[15];
  const float* b2   = (const float*)d_in[16];
  const float* wreg = (const float*)d_in[17];
  const float* breg = (const float*)d_in[18];
  const float* wcls = (const float*)d_in[19];
  const float* bcls = (const float*)d_in[20];
  float* out = (float*)d_out;

  char* ws = (char*)d_ws;
  float*          pooled = (float*)(ws + 0);
  unsigned short* tok    = (unsigned short*)(ws + 6422528);
  unsigned short* Qb     = (unsigned short*)(ws + 9633792);
  unsigned short* Kb     = (unsigned short*)(ws + 12845056);
  unsigned short* Vb     = (unsigned short*)(ws + 16056320);
  unsigned short* ctx    = (unsigned short*)(ws + 19267584);
  unsigned short* xb     = (unsigned short*)(ws + 22478848);  // live for fc1
  float*          h2f    = (float*)(ws + 25690112);
  unsigned short* h1     = (unsigned short*)(ws + 26738688);
  float*          wT     = (float*)(ws + 27787264);
  float*          logits = (float*)(ws + 28647424);
  unsigned short* w1p    = (unsigned short*)(ws + 29360128);  // 51,380,224 B
  unsigned short* w2p    = (unsigned short*)(ws + 80740352);  //  8,388,608 B -> ends 89,128,960
  float*          h1part = (float*)(ws + 0);   // 14 MB (pooled/tok/Qb/Kb dead by fc1)
  float*          h2part = (float*)(ws + 0);   // 16 MB (everything below ctx dead by fc2)

  pool_pack_kernel<<<1001,256,0,stream>>>(rois, fm0, fm1, fm2, fm3, pooled, tok,
                                          wreg, wcls, wT);

  // fused QKV (1176 gemm blocks) + w1 conversion tail (784 blocks, natural k)
  gemm_kernel<0,0,false><<<1176+784,256,0,stream>>>(tok, wq,wk,wv, nullptr, bq,bk,bv,
                                                    Qb,Kb,Vb, nullptr, nullptr,
                                                    6272,256,256, 98,12, 256,
                                                    1176, w1, w1p);

  attn_kernel<<<dim3(128,2),256,0,stream>>>(Qb, Kb, Vb, ctx);

  // O projection + residual (392 gemm blocks) + w2 conversion tail (128 blocks)
  gemm_kernel<1,0,false><<<392+128,256,0,stream>>>(ctx, wo,wo,wo, nullptr, bo,bo,bo,
                                                   xb,xb,xb, nullptr, pooled,
                                                   6272,256,256, 98,4, 256,
                                                   392, w2, w2p);

  // fc1: bf16 pages, split-K=14 -> 896 blocks, XCD slab remap
  gemm_kernel<2,1,true><<<896,256,0,stream>>>(xb, nullptr,nullptr,nullptr, w1p,
                                              nullptr,nullptr,nullptr, nullptr,nullptr,nullptr,
                                              h1part, nullptr, 128,2048,12544, 2,32, 896,
                                              896, nullptr, nullptr);
  reduce1_kernel<<<256,256,0,stream>>>(h1part, b1, h1, 14);

  // fc2: bf16 pages, split-K=16 -> 1024 blocks, XCD slab remap
  gemm_kernel<2,1,true><<<1024,256,0,stream>>>(h1, nullptr,nullptr,nullptr, w2p,
                                               nullptr,nullptr,nullptr, nullptr,nullptr,nullptr,
                                               h2part, nullptr, 128,2048,2048, 2,32, 128,
                                               1024, nullptr, nullptr);
  reduce2_kernel<<<256,256,0,stream>>>(h2part, h2f, 16);

  heads_dot<<<3360,256,0,stream>>>(h2f, b2, wT, breg, bcls, out, logits);
  cls_softmax<<<1,128,0,stream>>>(logits, out);
}

// Round 15
// 191.120 us; speedup vs baseline: 1.1121x; 1.1121x over previous
//
#include <hip/hip_runtime.h>
#include <hip/hip_bf16.h>
#include <stdint.h>

typedef __attribute__((ext_vector_type(8))) short bf16x8;
typedef __attribute__((ext_vector_type(4))) float f32x4;

__device__ __forceinline__ float blo(unsigned u){ union{float f;unsigned x;}v; v.x = u<<16; return v.f; }
__device__ __forceinline__ float bhi(unsigned u){ union{float f;unsigned x;}v; v.x = u & 0xFFFF0000u; return v.f; }
__device__ __forceinline__ unsigned short f2bf(float f){
  union{float f;unsigned x;}v; v.f=f; unsigned x=v.x;
  return (unsigned short)((x + 0x7fffu + ((x>>16)&1u)) >> 16);
}
__device__ __forceinline__ unsigned cvtpk(float lo, float hi){
  unsigned r;
  asm("v_cvt_pk_bf16_f32 %0, %1, %2" : "=v"(r) : "v"(lo), "v"(hi));
  return r;
}

// ---------------- ROI max-pool + token build + wT pack ----------------
// pooled/tok layout: [n][l][c]  (contiguous channel writes; K-order = l*256+c)
__global__ __launch_bounds__(256) void pool_pack_kernel(
    const float* __restrict__ rois,
    const float* __restrict__ fm0, const float* __restrict__ fm1,
    const float* __restrict__ fm2, const float* __restrict__ fm3,
    float* __restrict__ pooled, unsigned short* __restrict__ tok,
    const float* __restrict__ wreg, const float* __restrict__ wcls, float* __restrict__ wT)
{
  int bx = blockIdx.x;
  int tid = threadIdx.x;
  if (bx >= 896){
    int c = bx - 896;   // 0..104
    if (c < 84){
      for (int k = tid; k < 2048; k += 256) wT[(size_t)c*2048 + k] = wreg[(size_t)k*84 + c];
    } else {
      int cc = c - 84;
      for (int k = tid; k < 2048; k += 256) wT[(size_t)c*2048 + k] = wcls[(size_t)k*21 + cc];
    }
    return;
  }
  int n = bx / 7;            // roi
  int ph = bx - n*7;         // 0..6
  int c = tid;               // channel
  const float* r = rois + n*4;
  int b = n >> 6;
  float rx1=r[0], ry1=r[1], rx2=r[2], ry2=r[3];
  float size = sqrtf((rx2-rx1)*(ry2-ry1));
  int lvl = (int)(3.0f + logf(size/224.0f));
  if (lvl < 0) lvl = 0; if (lvl > 3) lvl = 3;
  const float strides_[4] = {4.f,8.f,16.f,32.f};
  const int hw_[4] = {160,80,40,20};
  float s = strides_[lvl]; int Hl = hw_[lvl];
  int x1 = (int)(rx1/s), y1 = (int)(ry1/s), x2 = (int)(rx2/s), y2 = (int)(ry2/s);
  #pragma unroll
  for (int it=0; it<7; ++it){
    bool need = (y2-y1+1) < 7;
    if (need){ y1 = (y1-1 > 0) ? y1-1 : 0; y2 = (y2+1 < Hl-1) ? y2+1 : Hl-1; }
  }
  #pragma unroll
  for (int it=0; it<7; ++it){
    bool need = (x2-x1+1) < 7;
    if (need){ x1 = (x1-1 > 0) ? x1-1 : 0; x2 = (x2+1 < Hl-1) ? x2+1 : Hl-1; }
  }
  int rh = y2-y1+1, rw = x2-x1+1;
  int kh = (rh+6)/7, sh = rh/7, kw = (rw+6)/7, sw2 = rw/7;
  const float* fm = (lvl==0)?fm0:(lvl==1)?fm1:(lvl==2)?fm2:fm3;
  const float* fp = fm + ((size_t)(b*256 + c))*(size_t)(Hl*Hl);
  int r0 = y1 + ph*sh;
  for (int pw=0; pw<7; ++pw){
    int c0 = x1 + pw*sw2;
    float m = -3.4e38f;
    for (int i=0;i<kh;++i){
      const float* rp = fp + (size_t)(r0+i)*Hl + c0;
      for (int j=0;j<kw;++j) m = fmaxf(m, rp[j]);
    }
    int l = ph*7+pw;
    pooled[((size_t)n*49 + l)*256 + c] = m;   // contiguous in c
    tok[((size_t)n*49 + l)*256 + c] = f2bf(m);
  }
}

// ---------------- standalone weight->page conversion, LDS-transpose, both sides contiguous ----------------
// Pages: P[pr][2048 shorts], pr = (kp>>5)*32 + bn; slot s (uint4): kr = s>>3,
// content = Wrow(kp = (kp>>5)*32+kr)[bn*64 + bcg*8..+7], bcg = (s&7)^((kr>>3)<<1).
// w1 K-order: kp = l*256+c -> src row = c*49+l (16 consecutive kp = same l, full-row reads).
// Block: 16 kp rows. Phase 1: 16x8KB contiguous f32 reads -> bf16 LDS [16][2048].
// Phase 2: thread (bn=t>>3, sub=t&7); per q: uint4 from LDS[q][bn*64+sub*8],
// dst slot s = krAbs*8 + (sub^((krAbs>>3)<<1)); 8 consecutive slots per (bn,q) = 128 B segs.
__global__ __launch_bounds__(256) void conv_kernel(
    const float* __restrict__ w1, unsigned short* __restrict__ w1p,
    const float* __restrict__ w2, unsigned short* __restrict__ w2p)
{
  __shared__ __align__(16) unsigned short L[16*2048];   // 64 KB
  int cb = blockIdx.x;
  const float* W; unsigned short* P; int kpBase; bool gather;
  if (cb < 784){ W = w1; P = w1p; kpBase = cb*16; gather = true; }
  else         { W = w2; P = w2p; kpBase = (cb-784)*16; gather = false; }
  int tid = threadIdx.x;
  for (int rep = 0; rep < 32; ++rep){
    int idx = rep*256 + tid;          // float4 index into 16 rows x 512 f4
    int row = idx >> 9, col4 = idx & 511;
    int kp = kpBase + row;
    size_t srow = gather ? ((size_t)(kp & 255)*49 + (size_t)(kp >> 8)) : (size_t)kp;
    float4 v = *(const float4*)(W + srow*2048 + (size_t)col4*4);
    uint2 w; w.x = cvtpk(v.x, v.y); w.y = cvtpk(v.z, v.w);
    *(uint2*)&L[row*2048 + col4*4] = w;
  }
  __syncthreads();
  int bn = tid >> 3, sub = tid & 7;
  int k32 = kpBase >> 5;
  int krHi = (kpBase >> 4) & 1;       // which half of the 32-k page chunk
  uint4* dstPage = (uint4*)(P + ((size_t)(k32*32 + bn))*2048);
  #pragma unroll
  for (int q = 0; q < 16; ++q){
    int krAbs = krHi*16 + q;
    int s = krAbs*8 + (sub ^ ((krAbs>>3)<<1));
    uint4 v = *(const uint4*)&L[q*2048 + bn*64 + sub*8];
    dstPage[s] = v;
  }
}

// ---------------- bf16 MFMA GEMM ----------------
// BSRC 0: B f32 [K][Nper] staged via float4+cvt (macro-128). BSRC 1: B = bf16 pages
// (1 contiguous uint4/thread/step). XCDR: kc-slab co-residency remap.
// EPI 0: out = val + bias. EPI 1: O-proj x[n][l*256+c] = val + bias + pooled[n][l][c].
// EPI 2: plain-store split-K partial.
template<int EPI, int BSRC, bool XCDR>
__global__ __launch_bounds__(256) void gemm_kernel(
    const unsigned short* __restrict__ A,
    const float* __restrict__ B0, const float* __restrict__ B1, const float* __restrict__ B2,
    const unsigned short* __restrict__ Bpre,
    const float* __restrict__ bias0, const float* __restrict__ bias1, const float* __restrict__ bias2,
    unsigned short* __restrict__ o0, unsigned short* __restrict__ o1, unsigned short* __restrict__ o2,
    float* __restrict__ outf, const float* __restrict__ pooled,
    int M, int Nper, int K, int nM, int nN, int kChunk)
{
  __shared__ __align__(16) unsigned short Bs[2][2048];
  int bid = blockIdx.x;
  if constexpr (XCDR){
    int pe = gridDim.x >> 3;
    bid = (bid & 7)*pe + (bid >> 3);
  }
  int tid = threadIdx.x;
  int per = nM*nN;
  int kc  = bid / per;
  int rem = bid - kc*per;
  int bm = rem % nM, bn = rem / nM;
  int m0 = bm*64, n0 = bn*64;
  int mat = n0 / Nper;
  int col0 = n0 - mat*Nper;
  const float* Bp    = (mat==0)?B0:(mat==1)?B1:B2;
  const float* biasp = (mat==0)?bias0:(mat==1)?bias1:bias2;
  unsigned short* outp = (mat==0)?o0:(mat==1)?o1:o2;
  int k0 = kc*kChunk;
  int nMacro = kChunk >> 7;
  int lane = tid & 63, wave = tid >> 6;
  int wm = wave & 1, wn = wave >> 1;
  int g = lane >> 4, c = lane & 15;

  f32x4 acc[2][2];
  #pragma unroll
  for (int i=0;i<2;++i)
    #pragma unroll
    for (int j=0;j<2;++j){ acc[i][j][0]=0.f; acc[i][j][1]=0.f; acc[i][j][2]=0.f; acc[i][j][3]=0.f; }

  int brow = tid >> 3, bcg = tid & 7;
  int bw_idx = brow*64 + ((bcg*8) ^ ((brow>>3)<<4));
  const float* Bbase = Bp + (size_t)brow*Nper + col0 + bcg*8;
  const unsigned short* Pbase = Bpre + (size_t)bn*2048 + tid*8;
  int rb0 = g*512 + (((wn*2  )^g)*16 + c);
  int rb1 = g*512 + (((wn*2+1)^g)*16 + c);
  const unsigned short* Ap0 = A + (size_t)(m0 + wm*32 +      c)*K + g*8;
  const unsigned short* Ap1 = A + (size_t)(m0 + wm*32 + 16 + c)*K + g*8;

  auto writeBf32 = [&](int buf, const float4& bx, const float4& by){
    uint4 w;
    w.x = cvtpk(bx.x,bx.y); w.y = cvtpk(bx.z,bx.w);
    w.z = cvtpk(by.x,by.y); w.w = cvtpk(by.z,by.w);
    *(uint4*)&Bs[buf][bw_idx] = w;
  };
  auto writeBpre = [&](int buf, const uint4& v){
    *(uint4*)&Bs[buf][tid*8] = v;
  };
  auto readFrags = [&](int buf, bf16x8& r0, bf16x8& r1){
    union { unsigned short s[8]; bf16x8 v; } u0, u1;
    const unsigned short* bsp = &Bs[buf][0];
    #pragma unroll
    for (int j=0;j<8;++j){ u0.s[j] = bsp[rb0 + j*64]; u1.s[j] = bsp[rb1 + j*64]; }
    r0 = u0.v; r1 = u1.v;
  };
  auto mfma4 = [&](const bf16x8& f0, const bf16x8& f1, const bf16x8& q0, const bf16x8& q1){
    acc[0][0] = __builtin_amdgcn_mfma_f32_16x16x32_bf16(f0,q0,acc[0][0],0,0,0);
    acc[0][1] = __builtin_amdgcn_mfma_f32_16x16x32_bf16(f0,q1,acc[0][1],0,0,0);
    acc[1][0] = __builtin_amdgcn_mfma_f32_16x16x32_bf16(f1,q0,acc[1][0],0,0,0);
    acc[1][1] = __builtin_amdgcn_mfma_f32_16x16x32_bf16(f1,q1,acc[1][1],0,0,0);
  };

  for (int mi = 0; mi < nMacro; ++mi){
    int kk = k0 + (mi << 7);
    uint4 a0x = *(const uint4*)(Ap0+kk),    a0y = *(const uint4*)(Ap1+kk);
    uint4 a1x = *(const uint4*)(Ap0+kk+32), a1y = *(const uint4*)(Ap1+kk+32);
    uint4 a2x = *(const uint4*)(Ap0+kk+64), a2y = *(const uint4*)(Ap1+kk+64);
    uint4 a3x = *(const uint4*)(Ap0+kk+96), a3y = *(const uint4*)(Ap1+kk+96);

    float4 b0a,b0b,b1a,b1b,b2a,b2b,b3a,b3b;
    uint4 v0,v1,v2,v3;
    if constexpr (BSRC==0){
      const float* p0 = Bbase + (size_t)kk*Nper;
      const float* p1 = p0 + (size_t)32*Nper;
      const float* p2 = p0 + (size_t)64*Nper;
      const float* p3 = p0 + (size_t)96*Nper;
      b0a = *(const float4*)p0; b0b = *(const float4*)(p0+4);
      b1a = *(const float4*)p1; b1b = *(const float4*)(p1+4);
      b2a = *(const float4*)p2; b2b = *(const float4*)(p2+4);
      b3a = *(const float4*)p3; b3b = *(const float4*)(p3+4);
    } else {
      const unsigned short* q = Pbase + (size_t)(kk>>5)*65536;   // ((k>>5)*32+bn)*2048
      v0 = *(const uint4*)q;
      v1 = *(const uint4*)(q + 65536);
      v2 = *(const uint4*)(q + 131072);
      v3 = *(const uint4*)(q + 196608);
    }

    if constexpr (BSRC==0) writeBf32(0,b0a,b0b); else writeBpre(0,v0);
    __syncthreads();

    bf16x8 q0,q1;
    readFrags(0,q0,q1);
    if constexpr (BSRC==0) writeBf32(1,b1a,b1b); else writeBpre(1,v1);
    mfma4(*(const bf16x8*)&a0x, *(const bf16x8*)&a0y, q0,q1);
    __syncthreads();

    readFrags(1,q0,q1);
    if constexpr (BSRC==0) writeBf32(0,b2a,b2b); else writeBpre(0,v2);
    mfma4(*(const bf16x8*)&a1x, *(const bf16x8*)&a1y, q0,q1);
    __syncthreads();

    readFrags(0,q0,q1);
    if constexpr (BSRC==0) writeBf32(1,b3a,b3b); else writeBpre(1,v3);
    mfma4(*(const bf16x8*)&a2x, *(const bf16x8*)&a2y, q0,q1);
    __syncthreads();

    readFrags(1,q0,q1);
    mfma4(*(const bf16x8*)&a3x, *(const bf16x8*)&a3y, q0,q1);
  }

  int rq = g << 2, cl = c;
  #pragma unroll
  for (int mr=0;mr<2;++mr){
    #pragma unroll
    for (int nc=0;nc<2;++nc){
      int rowb = m0 + wm*32 + mr*16 + rq;
      int colM = col0 + wn*32 + nc*16 + cl;
      #pragma unroll
      for (int r2=0;r2<4;++r2){
        float v = acc[mr][nc][r2];
        int rr = rowb + r2;
        if constexpr (EPI==0){
          v += biasp[colM];
          outp[(size_t)rr*Nper + colM] = f2bf(v);
        } else if constexpr (EPI==1){
          v += biasp[colM];
          v += pooled[(size_t)rr*256 + colM];                 // [n][l][c], lane-contiguous
          int nn = rr/49, l = rr - nn*49;
          outp[(size_t)nn*12544 + l*256 + colM] = f2bf(v);    // x in l*256+c order
        } else {
          outf[(size_t)kc*M*Nper + (size_t)rr*Nper + colM] = v;
        }
      }
    }
  }
}

// ---------------- split-K reduce kernels ----------------
__global__ __launch_bounds__(256) void reduce1_kernel(
    const float* __restrict__ part, const float* __restrict__ b1,
    unsigned short* __restrict__ h1, int nPart)
{
  int i = blockIdx.x*256 + threadIdx.x;      // float4 index, 65536 total
  float4 s = ((const float4*)part)[i];
  for (int kc = 1; kc < nPart; ++kc){
    float4 p = ((const float4*)part)[(size_t)kc*65536 + i];
    s.x += p.x; s.y += p.y; s.z += p.z; s.w += p.w;
  }
  float4 bb = *(const float4*)(b1 + ((i<<2) & 2047));
  s.x = fmaxf(s.x+bb.x,0.f); s.y = fmaxf(s.y+bb.y,0.f);
  s.z = fmaxf(s.z+bb.z,0.f); s.w = fmaxf(s.w+bb.w,0.f);
  uint2 w;
  w.x = cvtpk(s.x, s.y); w.y = cvtpk(s.z, s.w);
  *(uint2*)&h1[(size_t)i<<2] = w;
}

__global__ __launch_bounds__(256) void reduce2_kernel(
    const float* __restrict__ part, float* __restrict__ h2f, int nPart)
{
  int i = blockIdx.x*256 + threadIdx.x;
  float4 s = ((const float4*)part)[i];
  for (int kc = 1; kc < nPart; ++kc){
    float4 p = ((const float4*)part)[(size_t)kc*65536 + i];
    s.x += p.x; s.y += p.y; s.z += p.z; s.w += p.w;
  }
  ((float4*)h2f)[i] = s;
}

// ---------------- per-ROI attention: 2 blocks/roi, padded K/V rows ----------------
__global__ __launch_bounds__(256) void attn_kernel(
    const unsigned short* __restrict__ Q, const unsigned short* __restrict__ Km,
    const unsigned short* __restrict__ V, unsigned short* __restrict__ ctx)
{
  int n = blockIdx.x, half = blockIdx.y, tid = threadIdx.x;
  int r0 = half*25, rcnt = half ? 24 : 25;
  __shared__ __align__(16) unsigned short qs[25*256];
  __shared__ __align__(16) unsigned short ks[49*260];
  __shared__ float S[25*49];
  const uint4* qg = (const uint4*)(Q + ((size_t)n*49 + r0)*256);
  for (int i = tid; i < rcnt*32; i += 256) ((uint4*)qs)[i] = qg[i];
  const uint2* kg = (const uint2*)(Km + (size_t)n*49*256);
  for (int i = tid; i < 49*64; i += 256){
    int j = i >> 6, s = i & 63;
    *(uint2*)(ks + j*260 + s*4) = kg[i];
  }
  __syncthreads();
  for (int p = tid; p < rcnt*49; p += 256){
    int i = p/49, j = p - i*49;
    const uint2* qr = (const uint2*)(qs + i*256);
    const uint2* kr = (const uint2*)(ks + j*260);
    float sum = 0.f;
    #pragma unroll 8
    for (int c4 = 0; c4 < 64; ++c4){
      uint2 qv = qr[c4], kv = kr[c4];
      sum += blo(qv.x)*blo(kv.x) + bhi(qv.x)*bhi(kv.x);
      sum += blo(qv.y)*blo(kv.y) + bhi(qv.y)*bhi(kv.y);
    }
    S[p] = sum * (1.0f/16.0f);
  }
  __syncthreads();
  const uint2* vg = (const uint2*)(V + (size_t)n*49*256);
  for (int i = tid; i < 49*64; i += 256){
    int j = i >> 6, s = i & 63;
    *(uint2*)(ks + j*260 + s*4) = vg[i];
  }
  if (tid < rcnt){
    float* row = S + tid*49;
    float mx = row[0];
    for (int j=1;j<49;++j) mx = fmaxf(mx,row[j]);
    float sm = 0.f;
    for (int j=0;j<49;++j){ float e = expf(row[j]-mx); row[j]=e; sm+=e; }
    float inv = 1.0f/sm;
    for (int j=0;j<49;++j) row[j] *= inv;
  }
  __syncthreads();
  for (int idx = tid; idx < rcnt*64; idx += 256){
    int i = idx >> 6, cp4 = idx & 63;
    const float* att = S + i*49;
    float s0=0.f, s1=0.f, s2=0.f, s3=0.f;
    #pragma unroll 7
    for (int j=0;j<49;++j){
      uint2 v = *(const uint2*)(ks + j*260 + cp4*4);
      float a = att[j];
      s0 += a*blo(v.x); s1 += a*bhi(v.x);
      s2 += a*blo(v.y); s3 += a*bhi(v.y);
    }
    uint2 outw;
    outw.x = (unsigned)f2bf(s0) | ((unsigned)f2bf(s1) << 16);
    outw.y = (unsigned)f2bf(s2) | ((unsigned)f2bf(s3) << 16);
    *(uint2*)&ctx[((size_t)n*49 + r0 + i)*256 + cp4*4] = outw;
  }
}

// ---------------- heads: fused bias+relu on h2f ----------------
__global__ __launch_bounds__(256) void heads_dot(
    const float* __restrict__ h2f, const float* __restrict__ b2,
    const float* __restrict__ wT,
    const float* __restrict__ breg, const float* __restrict__ bcls,
    float* __restrict__ out, float* __restrict__ logits)
{
  int gw = (blockIdx.x*256 + threadIdx.x) >> 6;
  int lane = threadIdx.x & 63;
  int m = gw / 105, c = gw - m*105;
  const float4* hp = (const float4*)(h2f + (size_t)m*2048);
  const float4* bp = (const float4*)b2;
  const float4* wp = (const float4*)(wT + (size_t)c*2048);
  float sum = 0.f;
  #pragma unroll
  for (int i=0;i<8;++i){
    float4 a = hp[i*64 + lane];
    float4 bb = bp[i*64 + lane];
    float4 w = wp[i*64 + lane];
    sum += fmaxf(a.x+bb.x,0.f)*w.x + fmaxf(a.y+bb.y,0.f)*w.y
         + fmaxf(a.z+bb.z,0.f)*w.z + fmaxf(a.w+bb.w,0.f)*w.w;
  }
  #pragma unroll
  for (int off=32; off; off>>=1) sum += __shfl_down(sum, off, 64);
  if (lane == 0){
    if (c < 84) out[(size_t)m*84 + c] = sum + breg[c];
    else        logits[(size_t)m*21 + (c-84)] = sum + bcls[c-84];
  }
}

__global__ __launch_bounds__(128) void cls_softmax(
    const float* __restrict__ logits, float* __restrict__ out)
{
  int m = threadIdx.x;
  const float* lg = logits + (size_t)m*21;
  float mx = lg[0];
  #pragma unroll
  for (int j=1;j<21;++j) mx = fmaxf(mx, lg[j]);
  float sm = 0.f;
  float e[21];
  #pragma unroll
  for (int j=0;j<21;++j){ e[j] = expf(lg[j]-mx); sm += e[j]; }
  float inv = 1.0f/sm;
  #pragma unroll
  for (int j=0;j<21;++j) out[10752 + (size_t)m*21 + j] = e[j]*inv;
}

extern "C" void kernel_launch(void* const* d_in, const int* in_sizes, int n_in,
                              void* d_out, int out_size, void* d_ws, size_t ws_size,
                              hipStream_t stream)
{
  (void)in_sizes; (void)n_in; (void)out_size; (void)ws_size;
  const float* rois = (const float*)d_in[0];
  const float* fm0  = (const float*)d_in[1];
  const float* fm1  = (const float*)d_in[2];
  const float* fm2  = (const float*)d_in[3];
  const float* fm3  = (const float*)d_in[4];
  const float* wq   = (const float*)d_in[5];
  const float* bq   = (const float*)d_in[6];
  const float* wk   = (const float*)d_in[7];
  const float* bk   = (const float*)d_in[8];
  const float* wv   = (const float*)d_in[9];
  const float* bv   = (const float*)d_in[10];
  const float* wo   = (const float*)d_in[11];
  const float* bo   = (const float*)d_in[12];
  const float* w1   = (const float*)d_in[13];
  const float* b1   = (const float*)d_in[14];
  const float* w2   = (const float*)d_in[15];
  const float* b2   = (const float*)d_in[16];
  const float* wreg = (const float*)d_in[17];
  const float* breg = (const float*)d_in[18];
  const float* wcls = (const float*)d_in[19];
  const float* bcls = (const float*)d_in[20];
  float* out = (float*)d_out;

  char* ws = (char*)d_ws;
  float*          pooled = (float*)(ws + 0);
  unsigned short* tok    = (unsigned short*)(ws + 6422528);
  unsigned short* Qb     = (unsigned short*)(ws + 9633792);
  unsigned short* Kb     = (unsigned short*)(ws + 12845056);
  unsigned short* Vb     = (unsigned short*)(ws + 16056320);
  unsigned short* ctx    = (unsigned short*)(ws + 19267584);
  unsigned short* xb     = (unsigned short*)(ws + 22478848);  // live for fc1
  float*          h2f    = (float*)(ws + 25690112);
  unsigned short* h1     = (unsigned short*)(ws + 26738688);
  float*          wT     = (float*)(ws + 27787264);
  float*          logits = (float*)(ws + 28647424);
  unsigned short* w1p    = (unsigned short*)(ws + 29360128);  // 51,380,224 B
  unsigned short* w2p    = (unsigned short*)(ws + 80740352);  //  8,388,608 B -> ends 89,128,960
  float*          h1part = (float*)(ws + 0);   // 14 MB (pooled/tok/Qb/Kb dead by fc1)
  float*          h2part = (float*)(ws + 0);   // 16 MB (everything below ctx dead by fc2)

  pool_pack_kernel<<<1001,256,0,stream>>>(rois, fm0, fm1, fm2, fm3, pooled, tok,
                                          wreg, wcls, wT);

  // fused QKV: [6272,256] x 3x[256,256]  (no conversion tail)
  gemm_kernel<0,0,false><<<1176,256,0,stream>>>(tok, wq,wk,wv, nullptr, bq,bk,bv,
                                                Qb,Kb,Vb, nullptr, nullptr,
                                                6272,256,256, 98,12, 256);

  attn_kernel<<<dim3(128,2),256,0,stream>>>(Qb, Kb, Vb, ctx);

  // O projection + residual -> x[n][l*256+c]
  gemm_kernel<1,0,false><<<392,256,0,stream>>>(ctx, wo,wo,wo, nullptr, bo,bo,bo,
                                               xb,xb,xb, nullptr, pooled,
                                               6272,256,256, 98,4, 256);

  // weight conversion: LDS-transpose, both sides streaming (784 w1 + 128 w2 blocks)
  conv_kernel<<<912,256,0,stream>>>(w1, w1p, w2, w2p);

  // fc1: bf16 pages, split-K=14 -> 896 blocks, XCD slab remap
  gemm_kernel<2,1,true><<<896,256,0,stream>>>(xb, nullptr,nullptr,nullptr, w1p,
                                              nullptr,nullptr,nullptr, nullptr,nullptr,nullptr,
                                              h1part, nullptr, 128,2048,12544, 2,32, 896);
  reduce1_kernel<<<256,256,0,stream>>>(h1part, b1, h1, 14);

  // fc2: bf16 pages, split-K=16 -> 1024 blocks, XCD slab remap
  gemm_kernel<2,1,true><<<1024,256,0,stream>>>(h1, nullptr,nullptr,nullptr, w2p,
                                               nullptr,nullptr,nullptr, nullptr,nullptr,nullptr,
                                               h2part, nullptr, 128,2048,2048, 2,32, 128);
  reduce2_kernel<<<256,256,0,stream>>>(h2part, h2f, 16);

  heads_dot<<<3360,256,0,stream>>>(h2f, b2, wT, breg, bcls, out, logits);
  cls_softmax<<<1,128,0,stream>>>(logits, out);
}

// Round 16
// 186.462 us; speedup vs baseline: 1.1399x; 1.0250x over previous
//
#include <hip/hip_runtime.h>
#include <hip/hip_bf16.h>
#include <stdint.h>

typedef __attribute__((ext_vector_type(8))) short bf16x8;
typedef __attribute__((ext_vector_type(4))) float f32x4;

__device__ __forceinline__ float blo(unsigned u){ union{float f;unsigned x;}v; v.x = u<<16; return v.f; }
__device__ __forceinline__ float bhi(unsigned u){ union{float f;unsigned x;}v; v.x = u & 0xFFFF0000u; return v.f; }
__device__ __forceinline__ unsigned short f2bf(float f){
  union{float f;unsigned x;}v; v.f=f; unsigned x=v.x;
  return (unsigned short)((x + 0x7fffu + ((x>>16)&1u)) >> 16);
}
__device__ __forceinline__ unsigned cvtpk(float lo, float hi){
  unsigned r;
  asm("v_cvt_pk_bf16_f32 %0, %1, %2" : "=v"(r) : "v"(lo), "v"(hi));
  return r;
}

// ---------------- ROI max-pool + token build + wT pack ----------------
// pooled/tok layout: [n][l][c]  (contiguous channel writes; K-order = l*256+c)
__global__ __launch_bounds__(256) void pool_pack_kernel(
    const float* __restrict__ rois,
    const float* __restrict__ fm0, const float* __restrict__ fm1,
    const float* __restrict__ fm2, const float* __restrict__ fm3,
    float* __restrict__ pooled, unsigned short* __restrict__ tok,
    const float* __restrict__ wreg, const float* __restrict__ wcls, float* __restrict__ wT)
{
  int bx = blockIdx.x;
  int tid = threadIdx.x;
  if (bx >= 896){
    int c = bx - 896;   // 0..104
    if (c < 84){
      for (int k = tid; k < 2048; k += 256) wT[(size_t)c*2048 + k] = wreg[(size_t)k*84 + c];
    } else {
      int cc = c - 84;
      for (int k = tid; k < 2048; k += 256) wT[(size_t)c*2048 + k] = wcls[(size_t)k*21 + cc];
    }
    return;
  }
  int n = bx / 7;            // roi
  int ph = bx - n*7;         // 0..6
  int c = tid;               // channel
  const float* r = rois + n*4;
  int b = n >> 6;
  float rx1=r[0], ry1=r[1], rx2=r[2], ry2=r[3];
  float size = sqrtf((rx2-rx1)*(ry2-ry1));
  int lvl = (int)(3.0f + logf(size/224.0f));
  if (lvl < 0) lvl = 0; if (lvl > 3) lvl = 3;
  const float strides_[4] = {4.f,8.f,16.f,32.f};
  const int hw_[4] = {160,80,40,20};
  float s = strides_[lvl]; int Hl = hw_[lvl];
  int x1 = (int)(rx1/s), y1 = (int)(ry1/s), x2 = (int)(rx2/s), y2 = (int)(ry2/s);
  #pragma unroll
  for (int it=0; it<7; ++it){
    bool need = (y2-y1+1) < 7;
    if (need){ y1 = (y1-1 > 0) ? y1-1 : 0; y2 = (y2+1 < Hl-1) ? y2+1 : Hl-1; }
  }
  #pragma unroll
  for (int it=0; it<7; ++it){
    bool need = (x2-x1+1) < 7;
    if (need){ x1 = (x1-1 > 0) ? x1-1 : 0; x2 = (x2+1 < Hl-1) ? x2+1 : Hl-1; }
  }
  int rh = y2-y1+1, rw = x2-x1+1;
  int kh = (rh+6)/7, sh = rh/7, kw = (rw+6)/7, sw2 = rw/7;
  const float* fm = (lvl==0)?fm0:(lvl==1)?fm1:(lvl==2)?fm2:fm3;
  const float* fp = fm + ((size_t)(b*256 + c))*(size_t)(Hl*Hl);
  int r0 = y1 + ph*sh;
  for (int pw=0; pw<7; ++pw){
    int c0 = x1 + pw*sw2;
    float m = -3.4e38f;
    for (int i=0;i<kh;++i){
      const float* rp = fp + (size_t)(r0+i)*Hl + c0;
      for (int j=0;j<kw;++j) m = fmaxf(m, rp[j]);
    }
    int l = ph*7+pw;
    pooled[((size_t)n*49 + l)*256 + c] = m;   // contiguous in c
    tok[((size_t)n*49 + l)*256 + c] = f2bf(m);
  }
}

// ---------------- weight f32->bf16 conversion: pure grid-stride copy, zero LDS ----------------
// w1b row kp = l*256+c  <-  w1 row c*49+l  (row-permuted copy, both sides contiguous rows)
// w2b row k natural. 14592 rows x 512 float4. This is the m13 copy-ubench shape.
__global__ __launch_bounds__(256) void conv_kernel(
    const float* __restrict__ w1, unsigned short* __restrict__ w1b,
    const float* __restrict__ w2, unsigned short* __restrict__ w2b)
{
  const int total = (12544 + 2048) * 512;
  for (int idx = blockIdx.x*256 + threadIdx.x; idx < total; idx += gridDim.x*256){
    int row = idx >> 9, col4 = idx & 511;
    const float* src; unsigned short* dst;
    if (row < 12544){
      int l = row >> 8, c = row & 255;
      src = w1 + ((size_t)(c*49 + l))*2048;
      dst = w1b + (size_t)row*2048;
    } else {
      int r2 = row - 12544;
      src = w2 + (size_t)r2*2048;
      dst = w2b + (size_t)r2*2048;
    }
    float4 v = *(const float4*)(src + col4*4);
    uint2 w; w.x = cvtpk(v.x, v.y); w.y = cvtpk(v.z, v.w);
    *(uint2*)(dst + col4*4) = w;
  }
}

// ---------------- bf16 MFMA GEMM ----------------
// BSRC 0: B f32 [K][Nper] staged via float4+cvt. BSRC 2: B bf16 row-major [K][Nper],
// staged via one uint4/thread into the SAME swizzled LDS slot (identical image, no cvt).
// XCDR: kc-slab co-residency remap. EPI 0: out = val + bias.
// EPI 1: O-proj x[n][l*256+c] = val + bias + pooled[n][l][c]. EPI 2: split-K partial store.
template<int EPI, int BSRC, bool XCDR>
__global__ __launch_bounds__(256) void gemm_kernel(
    const unsigned short* __restrict__ A,
    const float* __restrict__ B0, const float* __restrict__ B1, const float* __restrict__ B2,
    const unsigned short* __restrict__ B16,
    const float* __restrict__ bias0, const float* __restrict__ bias1, const float* __restrict__ bias2,
    unsigned short* __restrict__ o0, unsigned short* __restrict__ o1, unsigned short* __restrict__ o2,
    float* __restrict__ outf, const float* __restrict__ pooled,
    int M, int Nper, int K, int nM, int nN, int kChunk)
{
  __shared__ __align__(16) unsigned short Bs[2][2048];
  int bid = blockIdx.x;
  if constexpr (XCDR){
    int pe = gridDim.x >> 3;
    bid = (bid & 7)*pe + (bid >> 3);
  }
  int tid = threadIdx.x;
  int per = nM*nN;
  int kc  = bid / per;
  int rem = bid - kc*per;
  int bm = rem % nM, bn = rem / nM;
  int m0 = bm*64, n0 = bn*64;
  int mat = n0 / Nper;
  int col0 = n0 - mat*Nper;
  const float* Bp    = (mat==0)?B0:(mat==1)?B1:B2;
  const float* biasp = (mat==0)?bias0:(mat==1)?bias1:bias2;
  unsigned short* outp = (mat==0)?o0:(mat==1)?o1:o2;
  int k0 = kc*kChunk;
  int nMacro = kChunk >> 7;
  int lane = tid & 63, wave = tid >> 6;
  int wm = wave & 1, wn = wave >> 1;
  int g = lane >> 4, c = lane & 15;

  f32x4 acc[2][2];
  #pragma unroll
  for (int i=0;i<2;++i)
    #pragma unroll
    for (int j=0;j<2;++j){ acc[i][j][0]=0.f; acc[i][j][1]=0.f; acc[i][j][2]=0.f; acc[i][j][3]=0.f; }

  int brow = tid >> 3, bcg = tid & 7;
  int bw_idx = brow*64 + ((bcg*8) ^ ((brow>>3)<<4));
  const float* Bbase = Bp + (size_t)brow*Nper + col0 + bcg*8;
  const unsigned short* B16base = B16 + (size_t)brow*Nper + col0 + bcg*8;
  int rb0 = g*512 + (((wn*2  )^g)*16 + c);
  int rb1 = g*512 + (((wn*2+1)^g)*16 + c);
  const unsigned short* Ap0 = A + (size_t)(m0 + wm*32 +      c)*K + g*8;
  const unsigned short* Ap1 = A + (size_t)(m0 + wm*32 + 16 + c)*K + g*8;

  auto writeBf32 = [&](int buf, const float4& bx, const float4& by){
    uint4 w;
    w.x = cvtpk(bx.x,bx.y); w.y = cvtpk(bx.z,bx.w);
    w.z = cvtpk(by.x,by.y); w.w = cvtpk(by.z,by.w);
    *(uint4*)&Bs[buf][bw_idx] = w;
  };
  auto writeB16 = [&](int buf, const uint4& v){
    *(uint4*)&Bs[buf][bw_idx] = v;
  };
  auto readFrags = [&](int buf, bf16x8& r0, bf16x8& r1){
    union { unsigned short s[8]; bf16x8 v; } u0, u1;
    const unsigned short* bsp = &Bs[buf][0];
    #pragma unroll
    for (int j=0;j<8;++j){ u0.s[j] = bsp[rb0 + j*64]; u1.s[j] = bsp[rb1 + j*64]; }
    r0 = u0.v; r1 = u1.v;
  };
  auto mfma4 = [&](const bf16x8& f0, const bf16x8& f1, const bf16x8& q0, const bf16x8& q1){
    acc[0][0] = __builtin_amdgcn_mfma_f32_16x16x32_bf16(f0,q0,acc[0][0],0,0,0);
    acc[0][1] = __builtin_amdgcn_mfma_f32_16x16x32_bf16(f0,q1,acc[0][1],0,0,0);
    acc[1][0] = __builtin_amdgcn_mfma_f32_16x16x32_bf16(f1,q0,acc[1][0],0,0,0);
    acc[1][1] = __builtin_amdgcn_mfma_f32_16x16x32_bf16(f1,q1,acc[1][1],0,0,0);
  };

  for (int mi = 0; mi < nMacro; ++mi){
    int kk = k0 + (mi << 7);
    uint4 a0x = *(const uint4*)(Ap0+kk),    a0y = *(const uint4*)(Ap1+kk);
    uint4 a1x = *(const uint4*)(Ap0+kk+32), a1y = *(const uint4*)(Ap1+kk+32);
    uint4 a2x = *(const uint4*)(Ap0+kk+64), a2y = *(const uint4*)(Ap1+kk+64);
    uint4 a3x = *(const uint4*)(Ap0+kk+96), a3y = *(const uint4*)(Ap1+kk+96);

    float4 b0a,b0b,b1a,b1b,b2a,b2b,b3a,b3b;
    uint4 v0,v1,v2,v3;
    if constexpr (BSRC==0){
      const float* p0 = Bbase + (size_t)kk*Nper;
      const float* p1 = p0 + (size_t)32*Nper;
      const float* p2 = p0 + (size_t)64*Nper;
      const float* p3 = p0 + (size_t)96*Nper;
      b0a = *(const float4*)p0; b0b = *(const float4*)(p0+4);
      b1a = *(const float4*)p1; b1b = *(const float4*)(p1+4);
      b2a = *(const float4*)p2; b2b = *(const float4*)(p2+4);
      b3a = *(const float4*)p3; b3b = *(const float4*)(p3+4);
    } else {
      const unsigned short* q = B16base + (size_t)kk*Nper;
      v0 = *(const uint4*)q;
      v1 = *(const uint4*)(q + (size_t)32*Nper);
      v2 = *(const uint4*)(q + (size_t)64*Nper);
      v3 = *(const uint4*)(q + (size_t)96*Nper);
    }

    if constexpr (BSRC==0) writeBf32(0,b0a,b0b); else writeB16(0,v0);
    __syncthreads();

    bf16x8 q0,q1;
    readFrags(0,q0,q1);
    if constexpr (BSRC==0) writeBf32(1,b1a,b1b); else writeB16(1,v1);
    mfma4(*(const bf16x8*)&a0x, *(const bf16x8*)&a0y, q0,q1);
    __syncthreads();

    readFrags(1,q0,q1);
    if constexpr (BSRC==0) writeBf32(0,b2a,b2b); else writeB16(0,v2);
    mfma4(*(const bf16x8*)&a1x, *(const bf16x8*)&a1y, q0,q1);
    __syncthreads();

    readFrags(0,q0,q1);
    if constexpr (BSRC==0) writeBf32(1,b3a,b3b); else writeB16(1,v3);
    mfma4(*(const bf16x8*)&a2x, *(const bf16x8*)&a2y, q0,q1);
    __syncthreads();

    readFrags(1,q0,q1);
    mfma4(*(const bf16x8*)&a3x, *(const bf16x8*)&a3y, q0,q1);
  }

  int rq = g << 2, cl = c;
  #pragma unroll
  for (int mr=0;mr<2;++mr){
    #pragma unroll
    for (int nc=0;nc<2;++nc){
      int rowb = m0 + wm*32 + mr*16 + rq;
      int colM = col0 + wn*32 + nc*16 + cl;
      #pragma unroll
      for (int r2=0;r2<4;++r2){
        float v = acc[mr][nc][r2];
        int rr = rowb + r2;
        if constexpr (EPI==0){
          v += biasp[colM];
          outp[(size_t)rr*Nper + colM] = f2bf(v);
        } else if constexpr (EPI==1){
          v += biasp[colM];
          v += pooled[(size_t)rr*256 + colM];                 // [n][l][c], lane-contiguous
          int nn = rr/49, l = rr - nn*49;
          outp[(size_t)nn*12544 + l*256 + colM] = f2bf(v);    // x in l*256+c order
        } else {
          outf[(size_t)kc*M*Nper + (size_t)rr*Nper + colM] = v;
        }
      }
    }
  }
}

// ---------------- split-K reduce kernels ----------------
__global__ __launch_bounds__(256) void reduce1_kernel(
    const float* __restrict__ part, const float* __restrict__ b1,
    unsigned short* __restrict__ h1, int nPart)
{
  int i = blockIdx.x*256 + threadIdx.x;      // float4 index, 65536 total
  float4 s = ((const float4*)part)[i];
  for (int kc = 1; kc < nPart; ++kc){
    float4 p = ((const float4*)part)[(size_t)kc*65536 + i];
    s.x += p.x; s.y += p.y; s.z += p.z; s.w += p.w;
  }
  float4 bb = *(const float4*)(b1 + ((i<<2) & 2047));
  s.x = fmaxf(s.x+bb.x,0.f); s.y = fmaxf(s.y+bb.y,0.f);
  s.z = fmaxf(s.z+bb.z,0.f); s.w = fmaxf(s.w+bb.w,0.f);
  uint2 w;
  w.x = cvtpk(s.x, s.y); w.y = cvtpk(s.z, s.w);
  *(uint2*)&h1[(size_t)i<<2] = w;
}

__global__ __launch_bounds__(256) void reduce2_kernel(
    const float* __restrict__ part, float* __restrict__ h2f, int nPart)
{
  int i = blockIdx.x*256 + threadIdx.x;
  float4 s = ((const float4*)part)[i];
  for (int kc = 1; kc < nPart; ++kc){
    float4 p = ((const float4*)part)[(size_t)kc*65536 + i];
    s.x += p.x; s.y += p.y; s.z += p.z; s.w += p.w;
  }
  ((float4*)h2f)[i] = s;
}

// ---------------- per-ROI attention: 2 blocks/roi, padded K/V rows ----------------
__global__ __launch_bounds__(256) void attn_kernel(
    const unsigned short* __restrict__ Q, const unsigned short* __restrict__ Km,
    const unsigned short* __restrict__ V, unsigned short* __restrict__ ctx)
{
  int n = blockIdx.x, half = blockIdx.y, tid = threadIdx.x;
  int r0 = half*25, rcnt = half ? 24 : 25;
  __shared__ __align__(16) unsigned short qs[25*256];
  __shared__ __align__(16) unsigned short ks[49*260];
  __shared__ float S[25*49];
  const uint4* qg = (const uint4*)(Q + ((size_t)n*49 + r0)*256);
  for (int i = tid; i < rcnt*32; i += 256) ((uint4*)qs)[i] = qg[i];
  const uint2* kg = (const uint2*)(Km + (size_t)n*49*256);
  for (int i = tid; i < 49*64; i += 256){
    int j = i >> 6, s = i & 63;
    *(uint2*)(ks + j*260 + s*4) = kg[i];
  }
  __syncthreads();
  for (int p = tid; p < rcnt*49; p += 256){
    int i = p/49, j = p - i*49;
    const uint2* qr = (const uint2*)(qs + i*256);
    const uint2* kr = (const uint2*)(ks + j*260);
    float sum = 0.f;
    #pragma unroll 8
    for (int c4 = 0; c4 < 64; ++c4){
      uint2 qv = qr[c4], kv = kr[c4];
      sum += blo(qv.x)*blo(kv.x) + bhi(qv.x)*bhi(kv.x);
      sum += blo(qv.y)*blo(kv.y) + bhi(qv.y)*bhi(kv.y);
    }
    S[p] = sum * (1.0f/16.0f);
  }
  __syncthreads();
  const uint2* vg = (const uint2*)(V + (size_t)n*49*256);
  for (int i = tid; i < 49*64; i += 256){
    int j = i >> 6, s = i & 63;
    *(uint2*)(ks + j*260 + s*4) = vg[i];
  }
  if (tid < rcnt){
    float* row = S + tid*49;
    float mx = row[0];
    for (int j=1;j<49;++j) mx = fmaxf(mx,row[j]);
    float sm = 0.f;
    for (int j=0;j<49;++j){ float e = expf(row[j]-mx); row[j]=e; sm+=e; }
    float inv = 1.0f/sm;
    for (int j=0;j<49;++j) row[j] *= inv;
  }
  __syncthreads();
  for (int idx = tid; idx < rcnt*64; idx += 256){
    int i = idx >> 6, cp4 = idx & 63;
    const float* att = S + i*49;
    float s0=0.f, s1=0.f, s2=0.f, s3=0.f;
    #pragma unroll 7
    for (int j=0;j<49;++j){
      uint2 v = *(const uint2*)(ks + j*260 + cp4*4);
      float a = att[j];
      s0 += a*blo(v.x); s1 += a*bhi(v.x);
      s2 += a*blo(v.y); s3 += a*bhi(v.y);
    }
    uint2 outw;
    outw.x = (unsigned)f2bf(s0) | ((unsigned)f2bf(s1) << 16);
    outw.y = (unsigned)f2bf(s2) | ((unsigned)f2bf(s3) << 16);
    *(uint2*)&ctx[((size_t)n*49 + r0 + i)*256 + cp4*4] = outw;
  }
}

// ---------------- heads: fused bias+relu on h2f ----------------
__global__ __launch_bounds__(256) void heads_dot(
    const float* __restrict__ h2f, const float* __restrict__ b2,
    const float* __restrict__ wT,
    const float* __restrict__ breg, const float* __restrict__ bcls,
    float* __restrict__ out, float* __restrict__ logits)
{
  int gw = (blockIdx.x*256 + threadIdx.x) >> 6;
  int lane = threadIdx.x & 63;
  int m = gw / 105, c = gw - m*105;
  const float4* hp = (const float4*)(h2f + (size_t)m*2048);
  const float4* bp = (const float4*)b2;
  const float4* wp = (const float4*)(wT + (size_t)c*2048);
  float sum = 0.f;
  #pragma unroll
  for (int i=0;i<8;++i){
    float4 a = hp[i*64 + lane];
    float4 bb = bp[i*64 + lane];
    float4 w = wp[i*64 + lane];
    sum += fmaxf(a.x+bb.x,0.f)*w.x + fmaxf(a.y+bb.y,0.f)*w.y
         + fmaxf(a.z+bb.z,0.f)*w.z + fmaxf(a.w+bb.w,0.f)*w.w;
  }
  #pragma unroll
  for (int off=32; off; off>>=1) sum += __shfl_down(sum, off, 64);
  if (lane == 0){
    if (c < 84) out[(size_t)m*84 + c] = sum + breg[c];
    else        logits[(size_t)m*21 + (c-84)] = sum + bcls[c-84];
  }
}

__global__ __launch_bounds__(128) void cls_softmax(
    const float* __restrict__ logits, float* __restrict__ out)
{
  int m = threadIdx.x;
  const float* lg = logits + (size_t)m*21;
  float mx = lg[0];
  #pragma unroll
  for (int j=1;j<21;++j) mx = fmaxf(mx, lg[j]);
  float sm = 0.f;
  float e[21];
  #pragma unroll
  for (int j=0;j<21;++j){ e[j] = expf(lg[j]-mx); sm += e[j]; }
  float inv = 1.0f/sm;
  #pragma unroll
  for (int j=0;j<21;++j) out[10752 + (size_t)m*21 + j] = e[j]*inv;
}

extern "C" void kernel_launch(void* const* d_in, const int* in_sizes, int n_in,
                              void* d_out, int out_size, void* d_ws, size_t ws_size,
                              hipStream_t stream)
{
  (void)in_sizes; (void)n_in; (void)out_size; (void)ws_size;
  const float* rois = (const float*)d_in[0];
  const float* fm0  = (const float*)d_in[1];
  const float* fm1  = (const float*)d_in[2];
  const float* fm2  = (const float*)d_in[3];
  const float* fm3  = (const float*)d_in[4];
  const float* wq   = (const float*)d_in[5];
  const float* bq   = (const float*)d_in[6];
  const float* wk   = (const float*)d_in[7];
  const float* bk   = (const float*)d_in[8];
  const float* wv   = (const float*)d_in[9];
  const float* bv   = (const float*)d_in[10];
  const float* wo   = (const float*)d_in[11];
  const float* bo   = (const float*)d_in[12];
  const float* w1   = (const float*)d_in[13];
  const float* b1   = (const float*)d_in[14];
  const float* w2   = (const float*)d_in[15];
  const float* b2   = (const float*)d_in[16];
  const float* wreg = (const float*)d_in[17];
  const float* breg = (const float*)d_in[18];
  const float* wcls = (const float*)d_in[19];
  const float* bcls = (const float*)d_in[20];
  float* out = (float*)d_out;

  char* ws = (char*)d_ws;
  float*          pooled = (float*)(ws + 0);
  unsigned short* tok    = (unsigned short*)(ws + 6422528);
  unsigned short* Qb     = (unsigned short*)(ws + 9633792);
  unsigned short* Kb     = (unsigned short*)(ws + 12845056);
  unsigned short* Vb     = (unsigned short*)(ws + 16056320);
  unsigned short* ctx    = (unsigned short*)(ws + 19267584);
  unsigned short* xb     = (unsigned short*)(ws + 22478848);  // live for fc1
  float*          h2f    = (float*)(ws + 25690112);
  unsigned short* h1     = (unsigned short*)(ws + 26738688);
  float*          wT     = (float*)(ws + 27787264);
  float*          logits = (float*)(ws + 28647424);
  unsigned short* w1b    = (unsigned short*)(ws + 29360128);  // 51,380,224 B (bf16 [12544][2048], kp-order)
  unsigned short* w2b    = (unsigned short*)(ws + 80740352);  //  8,388,608 B (bf16 [2048][2048])
  float*          h1part = (float*)(ws + 0);   // 14 MB (pooled/tok/Qb/Kb dead by fc1)
  float*          h2part = (float*)(ws + 0);   // 16 MB (everything below ctx dead by fc2)

  pool_pack_kernel<<<1001,256,0,stream>>>(rois, fm0, fm1, fm2, fm3, pooled, tok,
                                          wreg, wcls, wT);

  // weight conversion: pure grid-stride copy, zero LDS, 2048 blocks (occupancy test)
  conv_kernel<<<2048,256,0,stream>>>(w1, w1b, w2, w2b);

  // fused QKV: [6272,256] x 3x[256,256]
  gemm_kernel<0,0,false><<<1176,256,0,stream>>>(tok, wq,wk,wv, nullptr, bq,bk,bv,
                                                Qb,Kb,Vb, nullptr, nullptr,
                                                6272,256,256, 98,12, 256);

  attn_kernel<<<dim3(128,2),256,0,stream>>>(Qb, Kb, Vb, ctx);

  // O projection + residual -> x[n][l*256+c]
  gemm_kernel<1,0,false><<<392,256,0,stream>>>(ctx, wo,wo,wo, nullptr, bo,bo,bo,
                                               xb,xb,xb, nullptr, pooled,
                                               6272,256,256, 98,4, 256);

  // fc1: bf16 rows, split-K=14 -> 896 blocks, XCD slab remap
  gemm_kernel<2,2,true><<<896,256,0,stream>>>(xb, nullptr,nullptr,nullptr, w1b,
                                              nullptr,nullptr,nullptr, nullptr,nullptr,nullptr,
                                              h1part, nullptr, 128,2048,12544, 2,32, 896);
  reduce1_kernel<<<256,256,0,stream>>>(h1part, b1, h1, 14);

  // fc2: bf16 rows, split-K=16 -> 1024 blocks, XCD slab remap
  gemm_kernel<2,2,true><<<1024,256,0,stream>>>(h1, nullptr,nullptr,nullptr, w2b,
                                               nullptr,nullptr,nullptr, nullptr,nullptr,nullptr,
                                               h2part, nullptr, 128,2048,2048, 2,32, 128);
  reduce2_kernel<<<256,256,0,stream>>>(h2part, h2f, 16);

  heads_dot<<<3360,256,0,stream>>>(h2f, b2, wT, breg, bcls, out, logits);
  cls_softmax<<<1,128,0,stream>>>(logits, out);
}

// Round 17
// 161.574 us; speedup vs baseline: 1.3155x; 1.1540x over previous
//
#include <hip/hip_runtime.h>
#include <hip/hip_bf16.h>
#include <stdint.h>

typedef __attribute__((ext_vector_type(8))) short bf16x8;
typedef __attribute__((ext_vector_type(4))) float f32x4;

__device__ __forceinline__ float blo(unsigned u){ union{float f;unsigned x;}v; v.x = u<<16; return v.f; }
__device__ __forceinline__ float bhi(unsigned u){ union{float f;unsigned x;}v; v.x = u & 0xFFFF0000u; return v.f; }
__device__ __forceinline__ unsigned short f2bf(float f){
  union{float f;unsigned x;}v; v.f=f; unsigned x=v.x;
  return (unsigned short)((x + 0x7fffu + ((x>>16)&1u)) >> 16);
}
__device__ __forceinline__ unsigned cvtpk(float lo, float hi){
  unsigned r;
  asm("v_cvt_pk_bf16_f32 %0, %1, %2" : "=v"(r) : "v"(lo), "v"(hi));
  return r;
}
__device__ __forceinline__ void gll16(const float* g, float* l){
  __builtin_amdgcn_global_load_lds(
      (const __attribute__((address_space(1))) unsigned int*)g,
      (__attribute__((address_space(3))) unsigned int*)l, 16, 0, 0);
}

// ---------------- ROI max-pool + token build + wT pack ----------------
// pooled/tok layout: [n][l][c]
__global__ __launch_bounds__(256) void pool_pack_kernel(
    const float* __restrict__ rois,
    const float* __restrict__ fm0, const float* __restrict__ fm1,
    const float* __restrict__ fm2, const float* __restrict__ fm3,
    float* __restrict__ pooled, unsigned short* __restrict__ tok,
    const float* __restrict__ wreg, const float* __restrict__ wcls, float* __restrict__ wT)
{
  int bx = blockIdx.x;
  int tid = threadIdx.x;
  if (bx >= 896){
    int c = bx - 896;
    if (c < 84){
      for (int k = tid; k < 2048; k += 256) wT[(size_t)c*2048 + k] = wreg[(size_t)k*84 + c];
    } else {
      int cc = c - 84;
      for (int k = tid; k < 2048; k += 256) wT[(size_t)c*2048 + k] = wcls[(size_t)k*21 + cc];
    }
    return;
  }
  int n = bx / 7;
  int ph = bx - n*7;
  int c = tid;
  const float* r = rois + n*4;
  int b = n >> 6;
  float rx1=r[0], ry1=r[1], rx2=r[2], ry2=r[3];
  float size = sqrtf((rx2-rx1)*(ry2-ry1));
  int lvl = (int)(3.0f + logf(size/224.0f));
  if (lvl < 0) lvl = 0; if (lvl > 3) lvl = 3;
  const float strides_[4] = {4.f,8.f,16.f,32.f};
  const int hw_[4] = {160,80,40,20};
  float s = strides_[lvl]; int Hl = hw_[lvl];
  int x1 = (int)(rx1/s), y1 = (int)(ry1/s), x2 = (int)(rx2/s), y2 = (int)(ry2/s);
  #pragma unroll
  for (int it=0; it<7; ++it){
    bool need = (y2-y1+1) < 7;
    if (need){ y1 = (y1-1 > 0) ? y1-1 : 0; y2 = (y2+1 < Hl-1) ? y2+1 : Hl-1; }
  }
  #pragma unroll
  for (int it=0; it<7; ++it){
    bool need = (x2-x1+1) < 7;
    if (need){ x1 = (x1-1 > 0) ? x1-1 : 0; x2 = (x2+1 < Hl-1) ? x2+1 : Hl-1; }
  }
  int rh = y2-y1+1, rw = x2-x1+1;
  int kh = (rh+6)/7, sh = rh/7, kw = (rw+6)/7, sw2 = rw/7;
  const float* fm = (lvl==0)?fm0:(lvl==1)?fm1:(lvl==2)?fm2:fm3;
  const float* fp = fm + ((size_t)(b*256 + c))*(size_t)(Hl*Hl);
  int r0 = y1 + ph*sh;
  for (int pw=0; pw<7; ++pw){
    int c0 = x1 + pw*sw2;
    float m = -3.4e38f;
    for (int i=0;i<kh;++i){
      const float* rp = fp + (size_t)(r0+i)*Hl + c0;
      for (int j=0;j<kw;++j) m = fmaxf(m, rp[j]);
    }
    int l = ph*7+pw;
    pooled[((size_t)n*49 + l)*256 + c] = m;
    tok[((size_t)n*49 + l)*256 + c] = f2bf(m);
  }
}

// ---------------- fc GEMM: B f32 via global_load_lds, 4-buffer counted-vmcnt pipeline ----------------
// Tile M64xN64, Nper=2048 (nM=2, nN=32). kChunk/32 >= 3.
// GATHER: fc1's A (xb) K-order is l*256+c while w1 rows are c*49+l -> per k-row read
// w1 row (k&255)*49 + (k>>8) (full 8KB contiguous row; only the ORDER is permuted).
// Pipeline per step: s_waitcnt vmcnt(4) -> raw s_barrier -> A(i+1) reg prefetch ->
// gll stage buf (i+3)&3 -> ds_read f32 frags + cvt_pk -> 4 MFMA. 6 B-loads in flight.
template<bool GATHER>
__global__ __launch_bounds__(256) void fc_kernel(
    const unsigned short* __restrict__ A, const float* __restrict__ B,
    float* __restrict__ outf, int M, int K, int kChunk)
{
  __shared__ __align__(16) float Bs[4][32][64];   // 32 KB
  int bid = blockIdx.x;
  int pe = gridDim.x >> 3;
  bid = (bid & 7)*pe + (bid >> 3);                // XCD slab co-residency
  const int per = 64;
  int kc = bid / per;
  int rem = bid - kc*per;
  int bm = rem & 1, bn = rem >> 1;
  int m0 = bm*64, n0 = bn*64;
  int tid = threadIdx.x, lane = tid & 63, wave = tid >> 6;
  int wm = wave & 1, wn = wave >> 1;
  int g = lane >> 4, c = lane & 15;
  int k0 = kc*kChunk;
  int nSteps = kChunk >> 5;

  f32x4 acc[2][2];
  #pragma unroll
  for (int i=0;i<2;++i)
    #pragma unroll
    for (int j=0;j<2;++j){ acc[i][j][0]=0.f; acc[i][j][1]=0.f; acc[i][j][2]=0.f; acc[i][j][3]=0.f; }

  int rowInWave = lane >> 4;            // 0..3
  int colOff = n0 + (lane & 15)*4;
  const unsigned short* Ap0 = A + (size_t)(m0 + wm*32 +      c)*K + g*8;
  const unsigned short* Ap1 = A + (size_t)(m0 + wm*32 + 16 + c)*K + g*8;

  auto srcRow = [&](int k)->const float*{
    if constexpr (GATHER){ int kk = k; return B + ((size_t)((kk & 255)*49 + (kk >> 8)))*2048; }
    else                 { return B + (size_t)k*2048; }
  };
  auto stage = [&](int buf, int kk){
    int r0a = kk + wave*8 + rowInWave;
    int r0b = r0a + 4;
    gll16(srcRow(r0a) + colOff, &Bs[buf][wave*8    ][0]);
    gll16(srcRow(r0b) + colOff, &Bs[buf][wave*8 + 4][0]);
  };

  stage(0, k0); stage(1, k0+32); stage(2, k0+64);
  uint4 aCur0 = *(const uint4*)(Ap0 + k0);
  uint4 aCur1 = *(const uint4*)(Ap1 + k0);

  for (int i = 0; i < nSteps; ++i){
    int kk = k0 + (i<<5);
    int pend = nSteps - i;
    if (pend >= 3)      asm volatile("s_waitcnt vmcnt(4)" ::: "memory");
    else if (pend == 2) asm volatile("s_waitcnt vmcnt(2)" ::: "memory");
    else                asm volatile("s_waitcnt vmcnt(0)" ::: "memory");
    __builtin_amdgcn_s_barrier();

    uint4 aNxt0 = aCur0, aNxt1 = aCur1;
    if (i+1 < nSteps){
      aNxt0 = *(const uint4*)(Ap0 + kk + 32);
      aNxt1 = *(const uint4*)(Ap1 + kk + 32);
    }
    if (i+3 < nSteps) stage((i+3)&3, kk + 96);

    const float* fb = &Bs[i&3][g*8][wn*32 + c];
    float q0f[8], q1f[8];
    #pragma unroll
    for (int j=0;j<8;++j){ q0f[j] = fb[j*64]; q1f[j] = fb[j*64 + 16]; }
    union { unsigned u[4]; bf16x8 v; } q0u, q1u;
    q0u.u[0]=cvtpk(q0f[0],q0f[1]); q0u.u[1]=cvtpk(q0f[2],q0f[3]);
    q0u.u[2]=cvtpk(q0f[4],q0f[5]); q0u.u[3]=cvtpk(q0f[6],q0f[7]);
    q1u.u[0]=cvtpk(q1f[0],q1f[1]); q1u.u[1]=cvtpk(q1f[2],q1f[3]);
    q1u.u[2]=cvtpk(q1f[4],q1f[5]); q1u.u[3]=cvtpk(q1f[6],q1f[7]);
    bf16x8 f0 = *(const bf16x8*)&aCur0;
    bf16x8 f1 = *(const bf16x8*)&aCur1;
    acc[0][0] = __builtin_amdgcn_mfma_f32_16x16x32_bf16(f0,q0u.v,acc[0][0],0,0,0);
    acc[0][1] = __builtin_amdgcn_mfma_f32_16x16x32_bf16(f0,q1u.v,acc[0][1],0,0,0);
    acc[1][0] = __builtin_amdgcn_mfma_f32_16x16x32_bf16(f1,q0u.v,acc[1][0],0,0,0);
    acc[1][1] = __builtin_amdgcn_mfma_f32_16x16x32_bf16(f1,q1u.v,acc[1][1],0,0,0);
    aCur0 = aNxt0; aCur1 = aNxt1;
  }

  int rq = g << 2;
  #pragma unroll
  for (int mr=0;mr<2;++mr){
    #pragma unroll
    for (int nc=0;nc<2;++nc){
      int rowb = m0 + wm*32 + mr*16 + rq;
      int colM = n0 + wn*32 + nc*16 + c;
      #pragma unroll
      for (int r2=0;r2<4;++r2){
        outf[(size_t)kc*M*2048 + (size_t)(rowb+r2)*2048 + colM] = acc[mr][nc][r2];
      }
    }
  }
}

// ---------------- generic bf16 MFMA GEMM (QKV / O-proj) ----------------
template<int EPI>
__global__ __launch_bounds__(256) void gemm_kernel(
    const unsigned short* __restrict__ A,
    const float* __restrict__ B0, const float* __restrict__ B1, const float* __restrict__ B2,
    const float* __restrict__ bias0, const float* __restrict__ bias1, const float* __restrict__ bias2,
    unsigned short* __restrict__ o0, unsigned short* __restrict__ o1, unsigned short* __restrict__ o2,
    const float* __restrict__ pooled,
    int M, int Nper, int K, int nM, int nN, int kChunk)
{
  __shared__ __align__(16) unsigned short Bs[2][2048];
  int bid = blockIdx.x;
  int tid = threadIdx.x;
  int per = nM*nN;
  int kc  = bid / per;
  int rem = bid - kc*per;
  int bm = rem % nM, bn = rem / nM;
  int m0 = bm*64, n0 = bn*64;
  int mat = n0 / Nper;
  int col0 = n0 - mat*Nper;
  const float* Bp    = (mat==0)?B0:(mat==1)?B1:B2;
  const float* biasp = (mat==0)?bias0:(mat==1)?bias1:bias2;
  unsigned short* outp = (mat==0)?o0:(mat==1)?o1:o2;
  int k0 = kc*kChunk;
  int nMacro = kChunk >> 7;
  int lane = tid & 63, wave = tid >> 6;
  int wm = wave & 1, wn = wave >> 1;
  int g = lane >> 4, c = lane & 15;

  f32x4 acc[2][2];
  #pragma unroll
  for (int i=0;i<2;++i)
    #pragma unroll
    for (int j=0;j<2;++j){ acc[i][j][0]=0.f; acc[i][j][1]=0.f; acc[i][j][2]=0.f; acc[i][j][3]=0.f; }

  int brow = tid >> 3, bcg = tid & 7;
  int bw_idx = brow*64 + ((bcg*8) ^ ((brow>>3)<<4));
  const float* Bbase = Bp + (size_t)brow*Nper + col0 + bcg*8;
  int rb0 = g*512 + (((wn*2  )^g)*16 + c);
  int rb1 = g*512 + (((wn*2+1)^g)*16 + c);
  const unsigned short* Ap0 = A + (size_t)(m0 + wm*32 +      c)*K + g*8;
  const unsigned short* Ap1 = A + (size_t)(m0 + wm*32 + 16 + c)*K + g*8;

  auto writeB = [&](int buf, const float4& bx, const float4& by){
    uint4 w;
    w.x = cvtpk(bx.x,bx.y); w.y = cvtpk(bx.z,bx.w);
    w.z = cvtpk(by.x,by.y); w.w = cvtpk(by.z,by.w);
    *(uint4*)&Bs[buf][bw_idx] = w;
  };
  auto readFrags = [&](int buf, bf16x8& r0, bf16x8& r1){
    union { unsigned short s[8]; bf16x8 v; } u0, u1;
    const unsigned short* bsp = &Bs[buf][0];
    #pragma unroll
    for (int j=0;j<8;++j){ u0.s[j] = bsp[rb0 + j*64]; u1.s[j] = bsp[rb1 + j*64]; }
    r0 = u0.v; r1 = u1.v;
  };
  auto mfma4 = [&](const bf16x8& f0, const bf16x8& f1, const bf16x8& q0, const bf16x8& q1){
    acc[0][0] = __builtin_amdgcn_mfma_f32_16x16x32_bf16(f0,q0,acc[0][0],0,0,0);
    acc[0][1] = __builtin_amdgcn_mfma_f32_16x16x32_bf16(f0,q1,acc[0][1],0,0,0);
    acc[1][0] = __builtin_amdgcn_mfma_f32_16x16x32_bf16(f1,q0,acc[1][0],0,0,0);
    acc[1][1] = __builtin_amdgcn_mfma_f32_16x16x32_bf16(f1,q1,acc[1][1],0,0,0);
  };

  for (int mi = 0; mi < nMacro; ++mi){
    int kk = k0 + (mi << 7);
    uint4 a0x = *(const uint4*)(Ap0+kk),    a0y = *(const uint4*)(Ap1+kk);
    uint4 a1x = *(const uint4*)(Ap0+kk+32), a1y = *(const uint4*)(Ap1+kk+32);
    uint4 a2x = *(const uint4*)(Ap0+kk+64), a2y = *(const uint4*)(Ap1+kk+64);
    uint4 a3x = *(const uint4*)(Ap0+kk+96), a3y = *(const uint4*)(Ap1+kk+96);
    const float* p0 = Bbase + (size_t)kk*Nper;
    const float* p1 = p0 + (size_t)32*Nper;
    const float* p2 = p0 + (size_t)64*Nper;
    const float* p3 = p0 + (size_t)96*Nper;
    float4 b0a = *(const float4*)p0, b0b = *(const float4*)(p0+4);
    float4 b1a = *(const float4*)p1, b1b = *(const float4*)(p1+4);
    float4 b2a = *(const float4*)p2, b2b = *(const float4*)(p2+4);
    float4 b3a = *(const float4*)p3, b3b = *(const float4*)(p3+4);

    writeB(0, b0a, b0b);
    __syncthreads();
    bf16x8 q0,q1;
    readFrags(0,q0,q1);
    writeB(1,b1a,b1b);
    mfma4(*(const bf16x8*)&a0x, *(const bf16x8*)&a0y, q0,q1);
    __syncthreads();
    readFrags(1,q0,q1);
    writeB(0,b2a,b2b);
    mfma4(*(const bf16x8*)&a1x, *(const bf16x8*)&a1y, q0,q1);
    __syncthreads();
    readFrags(0,q0,q1);
    writeB(1,b3a,b3b);
    mfma4(*(const bf16x8*)&a2x, *(const bf16x8*)&a2y, q0,q1);
    __syncthreads();
    readFrags(1,q0,q1);
    mfma4(*(const bf16x8*)&a3x, *(const bf16x8*)&a3y, q0,q1);
  }

  int rq = g << 2, cl = c;
  #pragma unroll
  for (int mr=0;mr<2;++mr){
    #pragma unroll
    for (int nc=0;nc<2;++nc){
      int rowb = m0 + wm*32 + mr*16 + rq;
      int colM = col0 + wn*32 + nc*16 + cl;
      #pragma unroll
      for (int r2=0;r2<4;++r2){
        float v = acc[mr][nc][r2];
        int rr = rowb + r2;
        if constexpr (EPI==0){
          v += biasp[colM];
          outp[(size_t)rr*Nper + colM] = f2bf(v);
        } else {
          v += biasp[colM];
          v += pooled[(size_t)rr*256 + colM];
          int nn = rr/49, l = rr - nn*49;
          outp[(size_t)nn*12544 + l*256 + colM] = f2bf(v);
        }
      }
    }
  }
}

// ---------------- split-K reduce kernels ----------------
__global__ __launch_bounds__(256) void reduce1_kernel(
    const float* __restrict__ part, const float* __restrict__ b1,
    unsigned short* __restrict__ h1, int nPart)
{
  int i = blockIdx.x*256 + threadIdx.x;
  float4 s = ((const float4*)part)[i];
  for (int kc = 1; kc < nPart; ++kc){
    float4 p = ((const float4*)part)[(size_t)kc*65536 + i];
    s.x += p.x; s.y += p.y; s.z += p.z; s.w += p.w;
  }
  float4 bb = *(const float4*)(b1 + ((i<<2) & 2047));
  s.x = fmaxf(s.x+bb.x,0.f); s.y = fmaxf(s.y+bb.y,0.f);
  s.z = fmaxf(s.z+bb.z,0.f); s.w = fmaxf(s.w+bb.w,0.f);
  uint2 w;
  w.x = cvtpk(s.x, s.y); w.y = cvtpk(s.z, s.w);
  *(uint2*)&h1[(size_t)i<<2] = w;
}

__global__ __launch_bounds__(256) void reduce2_kernel(
    const float* __restrict__ part, float* __restrict__ h2f, int nPart)
{
  int i = blockIdx.x*256 + threadIdx.x;
  float4 s = ((const float4*)part)[i];
  for (int kc = 1; kc < nPart; ++kc){
    float4 p = ((const float4*)part)[(size_t)kc*65536 + i];
    s.x += p.x; s.y += p.y; s.z += p.z; s.w += p.w;
  }
  ((float4*)h2f)[i] = s;
}

// ---------------- per-ROI attention ----------------
__global__ __launch_bounds__(256) void attn_kernel(
    const unsigned short* __restrict__ Q, const unsigned short* __restrict__ Km,
    const unsigned short* __restrict__ V, unsigned short* __restrict__ ctx)
{
  int n = blockIdx.x, half = blockIdx.y, tid = threadIdx.x;
  int r0 = half*25, rcnt = half ? 24 : 25;
  __shared__ __align__(16) unsigned short qs[25*256];
  __shared__ __align__(16) unsigned short ks[49*260];
  __shared__ float S[25*49];
  const uint4* qg = (const uint4*)(Q + ((size_t)n*49 + r0)*256);
  for (int i = tid; i < rcnt*32; i += 256) ((uint4*)qs)[i] = qg[i];
  const uint2* kg = (const uint2*)(Km + (size_t)n*49*256);
  for (int i = tid; i < 49*64; i += 256){
    int j = i >> 6, s = i & 63;
    *(uint2*)(ks + j*260 + s*4) = kg[i];
  }
  __syncthreads();
  for (int p = tid; p < rcnt*49; p += 256){
    int i = p/49, j = p - i*49;
    const uint2* qr = (const uint2*)(qs + i*256);
    const uint2* kr = (const uint2*)(ks + j*260);
    float sum = 0.f;
    #pragma unroll 8
    for (int c4 = 0; c4 < 64; ++c4){
      uint2 qv = qr[c4], kv = kr[c4];
      sum += blo(qv.x)*blo(kv.x) + bhi(qv.x)*bhi(kv.x);
      sum += blo(qv.y)*blo(kv.y) + bhi(qv.y)*bhi(kv.y);
    }
    S[p] = sum * (1.0f/16.0f);
  }
  __syncthreads();
  const uint2* vg = (const uint2*)(V + (size_t)n*49*256);
  for (int i = tid; i < 49*64; i += 256){
    int j = i >> 6, s = i & 63;
    *(uint2*)(ks + j*260 + s*4) = vg[i];
  }
  if (tid < rcnt){
    float* row = S + tid*49;
    float mx = row[0];
    for (int j=1;j<49;++j) mx = fmaxf(mx,row[j]);
    float sm = 0.f;
    for (int j=0;j<49;++j){ float e = expf(row[j]-mx); row[j]=e; sm+=e; }
    float inv = 1.0f/sm;
    for (int j=0;j<49;++j) row[j] *= inv;
  }
  __syncthreads();
  for (int idx = tid; idx < rcnt*64; idx += 256){
    int i = idx >> 6, cp4 = idx & 63;
    const float* att = S + i*49;
    float s0=0.f, s1=0.f, s2=0.f, s3=0.f;
    #pragma unroll 7
    for (int j=0;j<49;++j){
      uint2 v = *(const uint2*)(ks + j*260 + cp4*4);
      float a = att[j];
      s0 += a*blo(v.x); s1 += a*bhi(v.x);
      s2 += a*blo(v.y); s3 += a*bhi(v.y);
    }
    uint2 outw;
    outw.x = (unsigned)f2bf(s0) | ((unsigned)f2bf(s1) << 16);
    outw.y = (unsigned)f2bf(s2) | ((unsigned)f2bf(s3) << 16);
    *(uint2*)&ctx[((size_t)n*49 + r0 + i)*256 + cp4*4] = outw;
  }
}

// ---------------- heads ----------------
__global__ __launch_bounds__(256) void heads_dot(
    const float* __restrict__ h2f, const float* __restrict__ b2,
    const float* __restrict__ wT,
    const float* __restrict__ breg, const float* __restrict__ bcls,
    float* __restrict__ out, float* __restrict__ logits)
{
  int gw = (blockIdx.x*256 + threadIdx.x) >> 6;
  int lane = threadIdx.x & 63;
  int m = gw / 105, c = gw - m*105;
  const float4* hp = (const float4*)(h2f + (size_t)m*2048);
  const float4* bp = (const float4*)b2;
  const float4* wp = (const float4*)(wT + (size_t)c*2048);
  float sum = 0.f;
  #pragma unroll
  for (int i=0;i<8;++i){
    float4 a = hp[i*64 + lane];
    float4 bb = bp[i*64 + lane];
    float4 w = wp[i*64 + lane];
    sum += fmaxf(a.x+bb.x,0.f)*w.x + fmaxf(a.y+bb.y,0.f)*w.y
         + fmaxf(a.z+bb.z,0.f)*w.z + fmaxf(a.w+bb.w,0.f)*w.w;
  }
  #pragma unroll
  for (int off=32; off; off>>=1) sum += __shfl_down(sum, off, 64);
  if (lane == 0){
    if (c < 84) out[(size_t)m*84 + c] = sum + breg[c];
    else        logits[(size_t)m*21 + (c-84)] = sum + bcls[c-84];
  }
}

__global__ __launch_bounds__(128) void cls_softmax(
    const float* __restrict__ logits, float* __restrict__ out)
{
  int m = threadIdx.x;
  const float* lg = logits + (size_t)m*21;
  float mx = lg[0];
  #pragma unroll
  for (int j=1;j<21;++j) mx = fmaxf(mx, lg[j]);
  float sm = 0.f;
  float e[21];
  #pragma unroll
  for (int j=0;j<21;++j){ e[j] = expf(lg[j]-mx); sm += e[j]; }
  float inv = 1.0f/sm;
  #pragma unroll
  for (int j=0;j<21;++j) out[10752 + (size_t)m*21 + j] = e[j]*inv;
}

extern "C" void kernel_launch(void* const* d_in, const int* in_sizes, int n_in,
                              void* d_out, int out_size, void* d_ws, size_t ws_size,
                              hipStream_t stream)
{
  (void)in_sizes; (void)n_in; (void)out_size; (void)ws_size;
  const float* rois = (const float*)d_in[0];
  const float* fm0  = (const float*)d_in[1];
  const float* fm1  = (const float*)d_in[2];
  const float* fm2  = (const float*)d_in[3];
  const float* fm3  = (const float*)d_in[4];
  const float* wq   = (const float*)d_in[5];
  const float* bq   = (const float*)d_in[6];
  const float* wk   = (const float*)d_in[7];
  const float* bk   = (const float*)d_in[8];
  const float* wv   = (const float*)d_in[9];
  const float* bv   = (const float*)d_in[10];
  const float* wo   = (const float*)d_in[11];
  const float* bo   = (const float*)d_in[12];
  const float* w1   = (const float*)d_in[13];
  const float* b1   = (const float*)d_in[14];
  const float* w2   = (const float*)d_in[15];
  const float* b2   = (const float*)d_in[16];
  const float* wreg = (const float*)d_in[17];
  const float* breg = (const float*)d_in[18];
  const float* wcls = (const float*)d_in[19];
  const float* bcls = (const float*)d_in[20];
  float* out = (float*)d_out;

  char* ws = (char*)d_ws;
  float*          pooled = (float*)(ws + 0);
  unsigned short* tok    = (unsigned short*)(ws + 6422528);
  unsigned short* Qb     = (unsigned short*)(ws + 9633792);
  unsigned short* Kb     = (unsigned short*)(ws + 12845056);
  unsigned short* Vb     = (unsigned short*)(ws + 16056320);
  unsigned short* ctx    = (unsigned short*)(ws + 19267584);
  unsigned short* xb     = (unsigned short*)(ws + 22478848);
  float*          h2f    = (float*)(ws + 25690112);
  unsigned short* h1     = (unsigned short*)(ws + 26738688);
  float*          wT     = (float*)(ws + 27787264);
  float*          logits = (float*)(ws + 28647424);
  float*          h1part = (float*)(ws + 29360128);  // 28 MB
  float*          h2part = (float*)(ws + 29360128);  // 16 MB (sequential reuse)

  pool_pack_kernel<<<1001,256,0,stream>>>(rois, fm0, fm1, fm2, fm3, pooled, tok,
                                          wreg, wcls, wT);

  gemm_kernel<0><<<1176,256,0,stream>>>(tok, wq,wk,wv, bq,bk,bv,
                                        Qb,Kb,Vb, nullptr,
                                        6272,256,256, 98,12, 256);

  attn_kernel<<<dim3(128,2),256,0,stream>>>(Qb, Kb, Vb, ctx);

  gemm_kernel<1><<<392,256,0,stream>>>(ctx, wo,wo,wo, bo,bo,bo,
                                       xb,xb,xb, pooled,
                                       6272,256,256, 98,4, 256);

  // fc1: w1 f32 direct (row-gathered k-order), counted-vmcnt pipeline, split-K=28
  fc_kernel<true><<<1792,256,0,stream>>>(xb, w1, h1part, 128, 12544, 448);
  reduce1_kernel<<<256,256,0,stream>>>(h1part, b1, h1, 28);

  // fc2: w2 f32 direct, split-K=16 (kChunk 128, 4 steps)
  fc_kernel<false><<<1024,256,0,stream>>>(h1, w2, h2part, 128, 2048, 128);
  reduce2_kernel<<<256,256,0,stream>>>(h2part, h2f, 16);

  heads_dot<<<3360,256,0,stream>>>(h2f, b2, wT, breg, bcls, out, logits);
  cls_softmax<<<1,128,0,stream>>>(logits, out);
}